// Round 3
// baseline (962.681 us; speedup 1.0000x reference)
//
#include <hip/hip_runtime.h>
#include <hip/hip_bf16.h>

#define D_IN   100
#define D_HID  256
#define D_OUT  40
#define BN_EPS 1e-5f

// ---------------------------------------------------------------- CSR build: histogram of dst into cnt (=cursor array)
__global__ void hist_dst(const int* __restrict__ dst, int* __restrict__ cnt, int E) {
    int stride = gridDim.x * blockDim.x;
    for (int i = blockIdx.x * blockDim.x + threadIdx.x; i < E; i += stride)
        atomicAdd(&cnt[dst[i]], 1);
}

// ---------------------------------------------------------------- single-block exclusive scan of counts -> row_ptr, init cursor
__global__ __launch_bounds__(1024) void scan_counts(int* __restrict__ cnt_cursor,
                                                    int* __restrict__ rp, int N) {
    __shared__ int bufA[1024], bufB[1024];
    int tid = threadIdx.x;
    int L = (N + 1023) >> 10;
    int start = min(tid * L, N);
    int end = min(start + L, N);
    int s = 0;
    for (int i = start; i < end; ++i) s += cnt_cursor[i];
    bufA[tid] = s;
    __syncthreads();
    int* in = bufA; int* out = bufB;
    for (int off = 1; off < 1024; off <<= 1) {
        out[tid] = (tid >= off) ? (in[tid - off] + in[tid]) : in[tid];
        __syncthreads();
        int* t = in; in = out; out = t;
    }
    int base = (tid == 0) ? 0 : in[tid - 1];
    for (int i = start; i < end; ++i) {
        int cv = cnt_cursor[i];
        rp[i] = base;
        cnt_cursor[i] = base;      // cursor init for fill pass
        base += cv;
    }
    if (end == N) rp[N] = base;
}

// ---------------------------------------------------------------- fill CSR adjacency
__global__ void fill_csr(const int* __restrict__ src, const int* __restrict__ dst,
                         int* __restrict__ cursor, int* __restrict__ csr, int E) {
    int stride = gridDim.x * blockDim.x;
    for (int i = blockIdx.x * blockDim.x + threadIdx.x; i < E; i += stride) {
        int pos = atomicAdd(&cursor[dst[i]], 1);
        csr[pos] = src[i];
    }
}

// ---------------------------------------------------------------- gather-aggregate: out[n] = X[n] + sum_j X[csr_j] (+ bias)
// C4 = row length in float4 (25 for [N,100], 10 for [N,40])
template<int C4, bool BIAS>
__global__ __launch_bounds__(256) void gather_rows(const float* __restrict__ X,
        const int* __restrict__ rp, const int* __restrict__ csr,
        const float* __restrict__ bias,
        float* __restrict__ out, int N) {
    int t = blockIdx.x * blockDim.x + threadIdx.x;
    int n = t / C4;
    int c = t - n * C4;
    if (n >= N) return;
    const float4* Xc = (const float4*)X + c;
    float4 acc = Xc[(size_t)n * C4];
    int e0 = rp[n], e1 = rp[n + 1];
    for (int e = e0; e < e1; ++e) {
        int s = csr[e];
        float4 u = Xc[(size_t)s * C4];
        acc.x += u.x; acc.y += u.y; acc.z += u.z; acc.w += u.w;
    }
    if (BIAS) {
        float4 b = ((const float4*)bias)[c];
        acc.x += b.x; acc.y += b.y; acc.z += b.z; acc.w += b.w;
    }
    ((float4*)out)[(size_t)n * C4 + c] = acc;
}

// ---------------------------------------------------------------- GEMM1: h_pre = agg1[N,100] @ W1[100,256] + b1
// fused epilogue: column sum / sumsq of h_pre via 64-lane wave reduction + atomics
__global__ __launch_bounds__(256) void gemm1(const float* __restrict__ A, const float* __restrict__ W,
                                             const float* __restrict__ bias, float* __restrict__ C, int N,
                                             float* __restrict__ gsum, float* __restrict__ gsumsq) {
    __shared__ float At[64][33];
    __shared__ float Bt[32][64];
    int r0 = blockIdx.x * 64;
    int c0 = blockIdx.y * 64;
    int tid = threadIdx.x;
    int row = tid & 63;
    int cg  = tid >> 6;
    float acc[16];
    #pragma unroll
    for (int j = 0; j < 16; ++j) acc[j] = 0.f;

    for (int k0 = 0; k0 < D_IN; k0 += 32) {
        #pragma unroll
        for (int i = 0; i < 2; ++i) {
            int idx = i * 256 + tid;
            int r = idx >> 3, kk4 = idx & 7;
            int k = k0 + kk4 * 4;
            float4 v = make_float4(0.f, 0.f, 0.f, 0.f);
            if (r0 + r < N && k < D_IN)
                v = *(const float4*)(A + (size_t)(r0 + r) * D_IN + k);
            At[r][kk4 * 4 + 0] = v.x; At[r][kk4 * 4 + 1] = v.y;
            At[r][kk4 * 4 + 2] = v.z; At[r][kk4 * 4 + 3] = v.w;
        }
        #pragma unroll
        for (int i = 0; i < 2; ++i) {
            int idx = i * 256 + tid;
            int kk = idx >> 4, c4 = idx & 15;
            int k = k0 + kk;
            float4 v = make_float4(0.f, 0.f, 0.f, 0.f);
            if (k < D_IN)
                v = *(const float4*)(W + (size_t)k * D_HID + c0 + c4 * 4);
            Bt[kk][c4 * 4 + 0] = v.x; Bt[kk][c4 * 4 + 1] = v.y;
            Bt[kk][c4 * 4 + 2] = v.z; Bt[kk][c4 * 4 + 3] = v.w;
        }
        __syncthreads();
        #pragma unroll
        for (int kk = 0; kk < 32; ++kk) {
            float a = At[row][kk];
            #pragma unroll
            for (int j = 0; j < 16; ++j)
                acc[j] += a * Bt[kk][cg * 16 + j];
        }
        __syncthreads();
    }
    bool valid = (r0 + row) < N;
    float* outp = C + (size_t)(r0 + row) * D_HID + c0 + cg * 16;
    #pragma unroll
    for (int j = 0; j < 16; ++j) {
        float v = acc[j] + bias[c0 + cg * 16 + j];
        if (valid) outp[j] = v;
        float sv = valid ? v : 0.f;
        float qv = sv * sv;
        #pragma unroll
        for (int off = 32; off > 0; off >>= 1) {
            sv += __shfl_down(sv, off);
            qv += __shfl_down(qv, off);
        }
        if (row == 0) {
            atomicAdd(&gsum[c0 + cg * 16 + j], sv);
            atomicAdd(&gsumsq[c0 + cg * 16 + j], qv);
        }
    }
}

// ---------------------------------------------------------------- column stats for [N,40]
__global__ __launch_bounds__(256) void stats_out(const float* __restrict__ H, int total,
                                                 float* __restrict__ sum, float* __restrict__ sumsq) {
    __shared__ float ls[D_OUT], lq[D_OUT];
    if (threadIdx.x < D_OUT) { ls[threadIdx.x] = 0.f; lq[threadIdx.x] = 0.f; }
    __syncthreads();
    int stride = gridDim.x * blockDim.x;
    for (int i = blockIdx.x * blockDim.x + threadIdx.x; i < total; i += stride) {
        float v = H[i];
        int c = i % D_OUT;
        atomicAdd(&ls[c], v);
        atomicAdd(&lq[c], v * v);
    }
    __syncthreads();
    if (threadIdx.x < D_OUT) {
        atomicAdd(&sum[threadIdx.x], ls[threadIdx.x]);
        atomicAdd(&sumsq[threadIdx.x], lq[threadIdx.x]);
    }
}

// ---------------------------------------------------------------- bn(x) = x*scale + shift
__global__ void finalize_stats(const float* __restrict__ sum, const float* __restrict__ sumsq,
                               const float* __restrict__ gamma, const float* __restrict__ beta,
                               int n, float invN, float* __restrict__ scale, float* __restrict__ shift) {
    int c = blockIdx.x * blockDim.x + threadIdx.x;
    if (c < n) {
        float m = sum[c] * invN;
        float var = sumsq[c] * invN - m * m;
        float rstd = rsqrtf(var + BN_EPS);
        float sc = rstd * gamma[c];
        scale[c] = sc;
        shift[c] = beta[c] - m * sc;
    }
}

// ---------------------------------------------------------------- GEMM2 fused: z = relu(bn1(hpre)) @ W2   (no bias; added in gather)
__global__ __launch_bounds__(256) void gemm2f(const float* __restrict__ A, const float* __restrict__ W,
                                              const float* __restrict__ scale, const float* __restrict__ shift,
                                              float* __restrict__ Z, int N) {
    __shared__ float At[64][33];
    __shared__ float Bt[32][D_OUT];
    __shared__ float sc_l[D_HID], sh_l[D_HID];
    int tid = threadIdx.x;
    sc_l[tid] = scale[tid];
    sh_l[tid] = shift[tid];
    int r0 = blockIdx.x * 64;
    int row = tid & 63;
    int cg  = tid >> 6;
    float acc[10];
    #pragma unroll
    for (int j = 0; j < 10; ++j) acc[j] = 0.f;
    __syncthreads();

    for (int k0 = 0; k0 < D_HID; k0 += 32) {
        #pragma unroll
        for (int i = 0; i < 2; ++i) {
            int idx = i * 256 + tid;
            int r = idx >> 3, kk4 = idx & 7;
            int kb = k0 + kk4 * 4;
            float4 v = make_float4(0.f, 0.f, 0.f, 0.f);
            if (r0 + r < N)
                v = *(const float4*)(A + (size_t)(r0 + r) * D_HID + kb);
            At[r][kk4 * 4 + 0] = fmaxf(v.x * sc_l[kb + 0] + sh_l[kb + 0], 0.f);
            At[r][kk4 * 4 + 1] = fmaxf(v.y * sc_l[kb + 1] + sh_l[kb + 1], 0.f);
            At[r][kk4 * 4 + 2] = fmaxf(v.z * sc_l[kb + 2] + sh_l[kb + 2], 0.f);
            At[r][kk4 * 4 + 3] = fmaxf(v.w * sc_l[kb + 3] + sh_l[kb + 3], 0.f);
        }
        #pragma unroll
        for (int i = 0; i < 5; ++i) {
            int idx = i * 256 + tid;
            int kk = idx / D_OUT, c = idx - kk * D_OUT;
            Bt[kk][c] = W[(size_t)(k0 + kk) * D_OUT + c];
        }
        __syncthreads();
        #pragma unroll
        for (int kk = 0; kk < 32; ++kk) {
            float a = At[row][kk];
            #pragma unroll
            for (int j = 0; j < 10; ++j)
                acc[j] += a * Bt[kk][cg * 10 + j];
        }
        __syncthreads();
    }
    if (r0 + row < N) {
        float* out = Z + (size_t)(r0 + row) * D_OUT + cg * 10;
        #pragma unroll
        for (int j = 0; j < 10; ++j)
            out[j] = acc[j];
    }
}

// ---------------------------------------------------------------- BN2 + log_softmax, LDS-staged, 256 rows/block
__global__ __launch_bounds__(256) void bn_logsoftmax(const float* __restrict__ H, const float* __restrict__ scale,
                                                     const float* __restrict__ shift, float* __restrict__ out, int N) {
    __shared__ float buf[256 * 41];
    int r0 = blockIdx.x * 256;
    int tid = threadIdx.x;
    int nrow = min(256, N - r0);
    int total = nrow * D_OUT;
    for (int i = tid; i < total; i += 256)
        buf[i + i / D_OUT] = H[(size_t)r0 * D_OUT + i];
    __syncthreads();
    if (tid < nrow) {
        int base = tid * 41;
        float m = -1e30f;
        #pragma unroll
        for (int j = 0; j < D_OUT; ++j) {
            float v = buf[base + j] * scale[j] + shift[j];
            buf[base + j] = v;
            m = fmaxf(m, v);
        }
        float s = 0.f;
        #pragma unroll
        for (int j = 0; j < D_OUT; ++j)
            s += expf(buf[base + j] - m);
        float lse = m + logf(s);
        #pragma unroll
        for (int j = 0; j < D_OUT; ++j)
            buf[base + j] -= lse;
    }
    __syncthreads();
    for (int i = tid; i < total; i += 256)
        out[(size_t)r0 * D_OUT + i] = buf[i + i / D_OUT];
}

// =================================================================
extern "C" void kernel_launch(void* const* d_in, const int* in_sizes, int n_in,
                              void* d_out, int out_size, void* d_ws, size_t ws_size,
                              hipStream_t stream) {
    const float* x      = (const float*)d_in[0];
    const int*   ei     = (const int*)d_in[1];
    const float* W1     = (const float*)d_in[2];
    const float* b1     = (const float*)d_in[3];
    const float* W2     = (const float*)d_in[4];
    const float* b2     = (const float*)d_in[5];
    const float* gamma1 = (const float*)d_in[6];
    const float* beta1  = (const float*)d_in[7];
    const float* gamma2 = (const float*)d_in[8];
    const float* beta2  = (const float*)d_in[9];
    float* out = (float*)d_out;

    const int N = in_sizes[0] / D_IN;      // 50000
    const int E = in_sizes[1] / 2;         // 800000
    const int* src = ei;
    const int* dst = ei + E;

    // ---------------- workspace layout ----------------
    float* ws = (float*)d_ws;
    float* reg1 = ws;                                   // N*100  (agg1)
    float* hpre = reg1 + (size_t)N * D_IN;              // N*256
    float* z    = hpre + (size_t)N * D_HID;             // N*40   (projected layer-2 features)
    float* h2   = z    + (size_t)N * D_OUT;             // N*40
    float* stats = h2 + (size_t)N * D_OUT;              // 1280
    float* colsum1   = stats + 0;     // 256
    float* colsumsq1 = stats + 256;   // 256
    float* colsum2   = stats + 512;   // 40 (pad 64)
    float* colsumsq2 = stats + 576;   // 40 (pad 64)
    float* scale1    = stats + 640;   // 256
    float* shift1    = stats + 896;   // 256
    float* scale2    = stats + 1152;  // 40 (pad 64)
    float* shift2    = stats + 1216;  // 40 (pad 64)
    int* rp     = (int*)(stats + 1280);   // N+1
    int* cursor = rp + N + 1;             // N
    int* csr    = cursor + N;             // E

    hipMemsetAsync(stats, 0, 640 * sizeof(float), stream);
    hipMemsetAsync(cursor, 0, (size_t)N * sizeof(int), stream);

    // ---------------- CSR build (shared by both layers) ----------------
    hist_dst<<<1024, 256, 0, stream>>>(dst, cursor, E);
    scan_counts<<<1, 1024, 0, stream>>>(cursor, rp, N);
    fill_csr<<<1024, 256, 0, stream>>>(src, dst, cursor, csr, E);

    // ---------------- layer 1: gather(100) -> gemm1 (+stats fused) ----------------
    gather_rows<25, false><<<(N * 25 + 255) / 256, 256, 0, stream>>>(x, rp, csr, nullptr, reg1, N);
    gemm1<<<dim3((N + 63) / 64, D_HID / 64), 256, 0, stream>>>(reg1, W1, b1, hpre, N, colsum1, colsumsq1);
    finalize_stats<<<1, 256, 0, stream>>>(colsum1, colsumsq1, gamma1, beta1, D_HID, 1.0f / N, scale1, shift1);

    // ---------------- layer 2: project first (BN1+relu fused), then gather(40) ----------------
    gemm2f<<<(N + 63) / 64, 256, 0, stream>>>(hpre, W2, scale1, shift1, z, N);
    gather_rows<10, true><<<(N * 10 + 255) / 256, 256, 0, stream>>>(z, rp, csr, b2, h2, N);
    stats_out<<<1024, 256, 0, stream>>>(h2, N * D_OUT, colsum2, colsumsq2);
    finalize_stats<<<1, 64, 0, stream>>>(colsum2, colsumsq2, gamma2, beta2, D_OUT, 1.0f / N, scale2, shift2);

    // ---------------- BN2 + log_softmax ----------------
    bn_logsoftmax<<<(N + 255) / 256, 256, 0, stream>>>(h2, scale2, shift2, out, N);
}

// Round 4
// 503.889 us; speedup vs baseline: 1.9105x; 1.9105x over previous
//
#include <hip/hip_runtime.h>
#include <hip/hip_bf16.h>

#define D_IN   100
#define D_HID  256
#define D_OUT  40
#define BN_EPS 1e-5f

// ---------------------------------------------------------------- CSR build: histogram of dst into cnt (=cursor array)
__global__ void hist_dst(const int* __restrict__ dst, int* __restrict__ cnt, int E) {
    int stride = gridDim.x * blockDim.x;
    for (int i = blockIdx.x * blockDim.x + threadIdx.x; i < E; i += stride)
        atomicAdd(&cnt[dst[i]], 1);
}

// ---------------------------------------------------------------- single-block exclusive scan of counts -> row_ptr, init cursor
__global__ __launch_bounds__(1024) void scan_counts(int* __restrict__ cnt_cursor,
                                                    int* __restrict__ rp, int N) {
    __shared__ int bufA[1024], bufB[1024];
    int tid = threadIdx.x;
    int L = (N + 1023) >> 10;
    int start = min(tid * L, N);
    int end = min(start + L, N);
    int s = 0;
    for (int i = start; i < end; ++i) s += cnt_cursor[i];
    bufA[tid] = s;
    __syncthreads();
    int* in = bufA; int* out = bufB;
    for (int off = 1; off < 1024; off <<= 1) {
        out[tid] = (tid >= off) ? (in[tid - off] + in[tid]) : in[tid];
        __syncthreads();
        int* t = in; in = out; out = t;
    }
    int base = (tid == 0) ? 0 : in[tid - 1];
    for (int i = start; i < end; ++i) {
        int cv = cnt_cursor[i];
        rp[i] = base;
        cnt_cursor[i] = base;      // cursor init for fill pass
        base += cv;
    }
    if (end == N) rp[N] = base;
}

// ---------------------------------------------------------------- fill CSR adjacency
__global__ void fill_csr(const int* __restrict__ src, const int* __restrict__ dst,
                         int* __restrict__ cursor, int* __restrict__ csr, int E) {
    int stride = gridDim.x * blockDim.x;
    for (int i = blockIdx.x * blockDim.x + threadIdx.x; i < E; i += stride) {
        int pos = atomicAdd(&cursor[dst[i]], 1);
        csr[pos] = src[i];
    }
}

// ---------------------------------------------------------------- gather-aggregate: out[n] = X[n] + sum_j X[csr_j] (+ bias)
// C4 = row length in float4 (25 for [N,100], 10 for [N,40])
template<int C4, bool BIAS>
__global__ __launch_bounds__(256) void gather_rows(const float* __restrict__ X,
        const int* __restrict__ rp, const int* __restrict__ csr,
        const float* __restrict__ bias,
        float* __restrict__ out, int N) {
    int t = blockIdx.x * blockDim.x + threadIdx.x;
    int n = t / C4;
    int c = t - n * C4;
    if (n >= N) return;
    const float4* Xc = (const float4*)X + c;
    float4 acc = Xc[(size_t)n * C4];
    int e0 = rp[n], e1 = rp[n + 1];
    for (int e = e0; e < e1; ++e) {
        int s = csr[e];
        float4 u = Xc[(size_t)s * C4];
        acc.x += u.x; acc.y += u.y; acc.z += u.z; acc.w += u.w;
    }
    if (BIAS) {
        float4 b = ((const float4*)bias)[c];
        acc.x += b.x; acc.y += b.y; acc.z += b.z; acc.w += b.w;
    }
    ((float4*)out)[(size_t)n * C4 + c] = acc;
}

// ---------------------------------------------------------------- GEMM1: h_pre = agg1[N,100] @ W1[100,256] + b1
__global__ __launch_bounds__(256) void gemm1(const float* __restrict__ A, const float* __restrict__ W,
                                             const float* __restrict__ bias, float* __restrict__ C, int N) {
    __shared__ float At[64][33];
    __shared__ float Bt[32][64];
    int r0 = blockIdx.x * 64;
    int c0 = blockIdx.y * 64;
    int tid = threadIdx.x;
    int row = tid & 63;
    int cg  = tid >> 6;
    float acc[16];
    #pragma unroll
    for (int j = 0; j < 16; ++j) acc[j] = 0.f;

    for (int k0 = 0; k0 < D_IN; k0 += 32) {
        #pragma unroll
        for (int i = 0; i < 2; ++i) {
            int idx = i * 256 + tid;
            int r = idx >> 3, kk4 = idx & 7;
            int k = k0 + kk4 * 4;
            float4 v = make_float4(0.f, 0.f, 0.f, 0.f);
            if (r0 + r < N && k < D_IN)
                v = *(const float4*)(A + (size_t)(r0 + r) * D_IN + k);
            At[r][kk4 * 4 + 0] = v.x; At[r][kk4 * 4 + 1] = v.y;
            At[r][kk4 * 4 + 2] = v.z; At[r][kk4 * 4 + 3] = v.w;
        }
        #pragma unroll
        for (int i = 0; i < 2; ++i) {
            int idx = i * 256 + tid;
            int kk = idx >> 4, c4 = idx & 15;
            int k = k0 + kk;
            float4 v = make_float4(0.f, 0.f, 0.f, 0.f);
            if (k < D_IN)
                v = *(const float4*)(W + (size_t)k * D_HID + c0 + c4 * 4);
            Bt[kk][c4 * 4 + 0] = v.x; Bt[kk][c4 * 4 + 1] = v.y;
            Bt[kk][c4 * 4 + 2] = v.z; Bt[kk][c4 * 4 + 3] = v.w;
        }
        __syncthreads();
        #pragma unroll
        for (int kk = 0; kk < 32; ++kk) {
            float a = At[row][kk];
            #pragma unroll
            for (int j = 0; j < 16; ++j)
                acc[j] += a * Bt[kk][cg * 16 + j];
        }
        __syncthreads();
    }
    if (r0 + row < N) {
        float* out = C + (size_t)(r0 + row) * D_HID + c0 + cg * 16;
        #pragma unroll
        for (int j = 0; j < 16; ++j)
            out[j] = acc[j] + bias[c0 + cg * 16 + j];
    }
}

// ---------------------------------------------------------------- column stats for [N,256]
__global__ __launch_bounds__(256) void stats_hid(const float* __restrict__ H, int N,
                                                 float* __restrict__ sum, float* __restrict__ sumsq) {
    int c = threadIdx.x;
    float s = 0.f, q = 0.f;
    for (int r = blockIdx.x; r < N; r += gridDim.x) {
        float v = H[(size_t)r * D_HID + c];
        s += v; q += v * v;
    }
    atomicAdd(&sum[c], s);
    atomicAdd(&sumsq[c], q);
}

// ---------------------------------------------------------------- column stats for [N,40]
__global__ __launch_bounds__(256) void stats_out(const float* __restrict__ H, int total,
                                                 float* __restrict__ sum, float* __restrict__ sumsq) {
    __shared__ float ls[D_OUT], lq[D_OUT];
    if (threadIdx.x < D_OUT) { ls[threadIdx.x] = 0.f; lq[threadIdx.x] = 0.f; }
    __syncthreads();
    int stride = gridDim.x * blockDim.x;
    for (int i = blockIdx.x * blockDim.x + threadIdx.x; i < total; i += stride) {
        float v = H[i];
        int c = i % D_OUT;
        atomicAdd(&ls[c], v);
        atomicAdd(&lq[c], v * v);
    }
    __syncthreads();
    if (threadIdx.x < D_OUT) {
        atomicAdd(&sum[threadIdx.x], ls[threadIdx.x]);
        atomicAdd(&sumsq[threadIdx.x], lq[threadIdx.x]);
    }
}

// ---------------------------------------------------------------- bn(x) = x*scale + shift
__global__ void finalize_stats(const float* __restrict__ sum, const float* __restrict__ sumsq,
                               const float* __restrict__ gamma, const float* __restrict__ beta,
                               int n, float invN, float* __restrict__ scale, float* __restrict__ shift) {
    int c = blockIdx.x * blockDim.x + threadIdx.x;
    if (c < n) {
        float m = sum[c] * invN;
        float var = sumsq[c] * invN - m * m;
        float rstd = rsqrtf(var + BN_EPS);
        float sc = rstd * gamma[c];
        scale[c] = sc;
        shift[c] = beta[c] - m * sc;
    }
}

// ---------------------------------------------------------------- GEMM2 fused: z = relu(bn1(hpre)) @ W2   (no bias; added in gather)
__global__ __launch_bounds__(256) void gemm2f(const float* __restrict__ A, const float* __restrict__ W,
                                              const float* __restrict__ scale, const float* __restrict__ shift,
                                              float* __restrict__ Z, int N) {
    __shared__ float At[64][33];
    __shared__ float Bt[32][D_OUT];
    __shared__ float sc_l[D_HID], sh_l[D_HID];
    int tid = threadIdx.x;
    sc_l[tid] = scale[tid];
    sh_l[tid] = shift[tid];
    int r0 = blockIdx.x * 64;
    int row = tid & 63;
    int cg  = tid >> 6;
    float acc[10];
    #pragma unroll
    for (int j = 0; j < 10; ++j) acc[j] = 0.f;
    __syncthreads();

    for (int k0 = 0; k0 < D_HID; k0 += 32) {
        #pragma unroll
        for (int i = 0; i < 2; ++i) {
            int idx = i * 256 + tid;
            int r = idx >> 3, kk4 = idx & 7;
            int kb = k0 + kk4 * 4;
            float4 v = make_float4(0.f, 0.f, 0.f, 0.f);
            if (r0 + r < N)
                v = *(const float4*)(A + (size_t)(r0 + r) * D_HID + kb);
            At[r][kk4 * 4 + 0] = fmaxf(v.x * sc_l[kb + 0] + sh_l[kb + 0], 0.f);
            At[r][kk4 * 4 + 1] = fmaxf(v.y * sc_l[kb + 1] + sh_l[kb + 1], 0.f);
            At[r][kk4 * 4 + 2] = fmaxf(v.z * sc_l[kb + 2] + sh_l[kb + 2], 0.f);
            At[r][kk4 * 4 + 3] = fmaxf(v.w * sc_l[kb + 3] + sh_l[kb + 3], 0.f);
        }
        #pragma unroll
        for (int i = 0; i < 5; ++i) {
            int idx = i * 256 + tid;
            int kk = idx / D_OUT, c = idx - kk * D_OUT;
            Bt[kk][c] = W[(size_t)(k0 + kk) * D_OUT + c];
        }
        __syncthreads();
        #pragma unroll
        for (int kk = 0; kk < 32; ++kk) {
            float a = At[row][kk];
            #pragma unroll
            for (int j = 0; j < 10; ++j)
                acc[j] += a * Bt[kk][cg * 10 + j];
        }
        __syncthreads();
    }
    if (r0 + row < N) {
        float* out = Z + (size_t)(r0 + row) * D_OUT + cg * 10;
        #pragma unroll
        for (int j = 0; j < 10; ++j)
            out[j] = acc[j];
    }
}

// ---------------------------------------------------------------- BN2 + log_softmax, LDS-staged, 256 rows/block
__global__ __launch_bounds__(256) void bn_logsoftmax(const float* __restrict__ H, const float* __restrict__ scale,
                                                     const float* __restrict__ shift, float* __restrict__ out, int N) {
    __shared__ float buf[256 * 41];
    int r0 = blockIdx.x * 256;
    int tid = threadIdx.x;
    int nrow = min(256, N - r0);
    int total = nrow * D_OUT;
    for (int i = tid; i < total; i += 256)
        buf[i + i / D_OUT] = H[(size_t)r0 * D_OUT + i];
    __syncthreads();
    if (tid < nrow) {
        int base = tid * 41;
        float m = -1e30f;
        #pragma unroll
        for (int j = 0; j < D_OUT; ++j) {
            float v = buf[base + j] * scale[j] + shift[j];
            buf[base + j] = v;
            m = fmaxf(m, v);
        }
        float s = 0.f;
        #pragma unroll
        for (int j = 0; j < D_OUT; ++j)
            s += expf(buf[base + j] - m);
        float lse = m + logf(s);
        #pragma unroll
        for (int j = 0; j < D_OUT; ++j)
            buf[base + j] -= lse;
    }
    __syncthreads();
    for (int i = tid; i < total; i += 256)
        out[(size_t)r0 * D_OUT + i] = buf[i + i / D_OUT];
}

// =================================================================
extern "C" void kernel_launch(void* const* d_in, const int* in_sizes, int n_in,
                              void* d_out, int out_size, void* d_ws, size_t ws_size,
                              hipStream_t stream) {
    const float* x      = (const float*)d_in[0];
    const int*   ei     = (const int*)d_in[1];
    const float* W1     = (const float*)d_in[2];
    const float* b1     = (const float*)d_in[3];
    const float* W2     = (const float*)d_in[4];
    const float* b2     = (const float*)d_in[5];
    const float* gamma1 = (const float*)d_in[6];
    const float* beta1  = (const float*)d_in[7];
    const float* gamma2 = (const float*)d_in[8];
    const float* beta2  = (const float*)d_in[9];
    float* out = (float*)d_out;

    const int N = in_sizes[0] / D_IN;      // 50000
    const int E = in_sizes[1] / 2;         // 800000
    const int* src = ei;
    const int* dst = ei + E;

    // ---------------- workspace layout ----------------
    float* ws = (float*)d_ws;
    float* reg1 = ws;                                   // N*100  (agg1)
    float* hpre = reg1 + (size_t)N * D_IN;              // N*256
    float* z    = hpre + (size_t)N * D_HID;             // N*40   (projected layer-2 features)
    float* h2   = z    + (size_t)N * D_OUT;             // N*40
    float* stats = h2 + (size_t)N * D_OUT;              // 1280
    float* colsum1   = stats + 0;     // 256
    float* colsumsq1 = stats + 256;   // 256
    float* colsum2   = stats + 512;   // 40 (pad 64)
    float* colsumsq2 = stats + 576;   // 40 (pad 64)
    float* scale1    = stats + 640;   // 256
    float* shift1    = stats + 896;   // 256
    float* scale2    = stats + 1152;  // 40 (pad 64)
    float* shift2    = stats + 1216;  // 40 (pad 64)
    int* rp     = (int*)(stats + 1280);   // N+1
    int* cursor = rp + N + 1;             // N
    int* csr    = cursor + N;             // E

    hipMemsetAsync(stats, 0, 640 * sizeof(float), stream);
    hipMemsetAsync(cursor, 0, (size_t)N * sizeof(int), stream);

    // ---------------- CSR build (shared by both layers) ----------------
    hist_dst<<<1024, 256, 0, stream>>>(dst, cursor, E);
    scan_counts<<<1, 1024, 0, stream>>>(cursor, rp, N);
    fill_csr<<<1024, 256, 0, stream>>>(src, dst, cursor, csr, E);

    // ---------------- layer 1: gather(100) -> gemm1 -> stats ----------------
    gather_rows<25, false><<<(N * 25 + 255) / 256, 256, 0, stream>>>(x, rp, csr, nullptr, reg1, N);
    gemm1<<<dim3((N + 63) / 64, D_HID / 64), 256, 0, stream>>>(reg1, W1, b1, hpre, N);
    stats_hid<<<512, 256, 0, stream>>>(hpre, N, colsum1, colsumsq1);
    finalize_stats<<<1, 256, 0, stream>>>(colsum1, colsumsq1, gamma1, beta1, D_HID, 1.0f / N, scale1, shift1);

    // ---------------- layer 2: project first (BN1+relu fused), then gather(40) ----------------
    gemm2f<<<(N + 63) / 64, 256, 0, stream>>>(hpre, W2, scale1, shift1, z, N);
    gather_rows<10, true><<<(N * 10 + 255) / 256, 256, 0, stream>>>(z, rp, csr, b2, h2, N);
    stats_out<<<1024, 256, 0, stream>>>(h2, N * D_OUT, colsum2, colsumsq2);
    finalize_stats<<<1, 64, 0, stream>>>(colsum2, colsumsq2, gamma2, beta2, D_OUT, 1.0f / N, scale2, shift2);

    // ---------------- BN2 + log_softmax ----------------
    bn_logsoftmax<<<(N + 255) / 256, 256, 0, stream>>>(h2, scale2, shift2, out, N);
}

// Round 5
// 400.530 us; speedup vs baseline: 2.4035x; 1.2581x over previous
//
#include <hip/hip_runtime.h>
#include <hip/hip_bf16.h>

#define D_IN   100
#define D_HID  256
#define D_OUT  40
#define BN_EPS 1e-5f
#define SCAN_CHUNK 512   // counts per block in hierarchical scan

// ---------------------------------------------------------------- CSR build: histogram of dst into cnt (=cursor array)
__global__ void hist_dst(const int* __restrict__ dst, int* __restrict__ cnt, int E) {
    int stride = gridDim.x * blockDim.x;
    for (int i = blockIdx.x * blockDim.x + threadIdx.x; i < E; i += stride)
        atomicAdd(&cnt[dst[i]], 1);
}

// ---------------------------------------------------------------- scan stage A: per-block sums of 512-count chunks
__global__ __launch_bounds__(256) void scan_blocksums(const int* __restrict__ cnt,
                                                      int* __restrict__ bsum, int N) {
    __shared__ int red[256];
    int i0 = blockIdx.x * SCAN_CHUNK + threadIdx.x * 2;
    int s = 0;
    if (i0 < N)     s += cnt[i0];
    if (i0 + 1 < N) s += cnt[i0 + 1];
    red[threadIdx.x] = s;
    __syncthreads();
    #pragma unroll
    for (int off = 128; off > 0; off >>= 1) {
        if (threadIdx.x < off) red[threadIdx.x] += red[threadIdx.x + off];
        __syncthreads();
    }
    if (threadIdx.x == 0) bsum[blockIdx.x] = red[0];
}

// ---------------------------------------------------------------- scan stage B: single tiny block scans block sums (nb <= 128)
__global__ __launch_bounds__(128) void scan_bsums(int* __restrict__ bsum, int nb,
                                                  int* __restrict__ rp, int N) {
    __shared__ int bufA[128], bufB[128];
    int tid = threadIdx.x;
    int v = (tid < nb) ? bsum[tid] : 0;
    bufA[tid] = v;
    __syncthreads();
    int* in = bufA; int* out = bufB;
    #pragma unroll
    for (int off = 1; off < 128; off <<= 1) {
        out[tid] = (tid >= off) ? (in[tid - off] + in[tid]) : in[tid];
        __syncthreads();
        int* t = in; in = out; out = t;
    }
    if (tid < nb) bsum[tid] = in[tid] - v;      // exclusive offsets
    if (tid == nb - 1) rp[N] = in[tid];         // total = E
}

// ---------------------------------------------------------------- scan stage C: local exclusive scan + block offset -> rp, cursor
__global__ __launch_bounds__(256) void scan_final(const int* __restrict__ cnt,
                                                  const int* __restrict__ boffs,
                                                  int* __restrict__ rp, int* __restrict__ cursor, int N) {
    __shared__ int bufA[256], bufB[256];
    int tid = threadIdx.x;
    int i0 = blockIdx.x * SCAN_CHUNK + tid * 2;
    int a0 = (i0 < N) ? cnt[i0] : 0;
    int a1 = (i0 + 1 < N) ? cnt[i0 + 1] : 0;
    int s = a0 + a1;
    bufA[tid] = s;
    __syncthreads();
    int* in = bufA; int* out = bufB;
    #pragma unroll
    for (int off = 1; off < 256; off <<= 1) {
        out[tid] = (tid >= off) ? (in[tid - off] + in[tid]) : in[tid];
        __syncthreads();
        int* t = in; in = out; out = t;
    }
    int base = boffs[blockIdx.x] + in[tid] - s;   // exclusive prefix
    if (i0 < N)     { rp[i0] = base;          cursor[i0] = base; }
    if (i0 + 1 < N) { rp[i0 + 1] = base + a0; cursor[i0 + 1] = base + a0; }
}

// ---------------------------------------------------------------- fill CSR adjacency
__global__ void fill_csr(const int* __restrict__ src, const int* __restrict__ dst,
                         int* __restrict__ cursor, int* __restrict__ csr, int E) {
    int stride = gridDim.x * blockDim.x;
    for (int i = blockIdx.x * blockDim.x + threadIdx.x; i < E; i += stride) {
        int pos = atomicAdd(&cursor[dst[i]], 1);
        csr[pos] = src[i];
    }
}

// ---------------------------------------------------------------- gather-aggregate: out[n] = X[n] + sum_j X[csr_j] (+ bias)
template<int C4, bool BIAS>
__global__ __launch_bounds__(256) void gather_rows(const float* __restrict__ X,
        const int* __restrict__ rp, const int* __restrict__ csr,
        const float* __restrict__ bias,
        float* __restrict__ out, int N) {
    int t = blockIdx.x * blockDim.x + threadIdx.x;
    int n = t / C4;
    int c = t - n * C4;
    if (n >= N) return;
    const float4* Xc = (const float4*)X + c;
    float4 acc = Xc[(size_t)n * C4];
    int e0 = rp[n], e1 = rp[n + 1];
    for (int e = e0; e < e1; ++e) {
        int s = csr[e];
        float4 u = Xc[(size_t)s * C4];
        acc.x += u.x; acc.y += u.y; acc.z += u.z; acc.w += u.w;
    }
    if (BIAS) {
        float4 b = ((const float4*)bias)[c];
        acc.x += b.x; acc.y += b.y; acc.z += b.z; acc.w += b.w;
    }
    ((float4*)out)[(size_t)n * C4 + c] = acc;
}

// ---------------------------------------------------------------- GEMM1: h_pre = agg1[N,100] @ W1[100,256] + b1
__global__ __launch_bounds__(256) void gemm1(const float* __restrict__ A, const float* __restrict__ W,
                                             const float* __restrict__ bias, float* __restrict__ C, int N) {
    __shared__ float At[64][33];
    __shared__ float Bt[32][64];
    int r0 = blockIdx.x * 64;
    int c0 = blockIdx.y * 64;
    int tid = threadIdx.x;
    int row = tid & 63;
    int cg  = tid >> 6;
    float acc[16];
    #pragma unroll
    for (int j = 0; j < 16; ++j) acc[j] = 0.f;

    for (int k0 = 0; k0 < D_IN; k0 += 32) {
        #pragma unroll
        for (int i = 0; i < 2; ++i) {
            int idx = i * 256 + tid;
            int r = idx >> 3, kk4 = idx & 7;
            int k = k0 + kk4 * 4;
            float4 v = make_float4(0.f, 0.f, 0.f, 0.f);
            if (r0 + r < N && k < D_IN)
                v = *(const float4*)(A + (size_t)(r0 + r) * D_IN + k);
            At[r][kk4 * 4 + 0] = v.x; At[r][kk4 * 4 + 1] = v.y;
            At[r][kk4 * 4 + 2] = v.z; At[r][kk4 * 4 + 3] = v.w;
        }
        #pragma unroll
        for (int i = 0; i < 2; ++i) {
            int idx = i * 256 + tid;
            int kk = idx >> 4, c4 = idx & 15;
            int k = k0 + kk;
            float4 v = make_float4(0.f, 0.f, 0.f, 0.f);
            if (k < D_IN)
                v = *(const float4*)(W + (size_t)k * D_HID + c0 + c4 * 4);
            Bt[kk][c4 * 4 + 0] = v.x; Bt[kk][c4 * 4 + 1] = v.y;
            Bt[kk][c4 * 4 + 2] = v.z; Bt[kk][c4 * 4 + 3] = v.w;
        }
        __syncthreads();
        #pragma unroll
        for (int kk = 0; kk < 32; ++kk) {
            float a = At[row][kk];
            #pragma unroll
            for (int j = 0; j < 16; ++j)
                acc[j] += a * Bt[kk][cg * 16 + j];
        }
        __syncthreads();
    }
    if (r0 + row < N) {
        float* out = C + (size_t)(r0 + row) * D_HID + c0 + cg * 16;
        #pragma unroll
        for (int j = 0; j < 16; ++j)
            out[j] = acc[j] + bias[c0 + cg * 16 + j];
    }
}

// ---------------------------------------------------------------- column stats for [N,256]
__global__ __launch_bounds__(256) void stats_hid(const float* __restrict__ H, int N,
                                                 float* __restrict__ sum, float* __restrict__ sumsq) {
    int c = threadIdx.x;
    float s = 0.f, q = 0.f;
    for (int r = blockIdx.x; r < N; r += gridDim.x) {
        float v = H[(size_t)r * D_HID + c];
        s += v; q += v * v;
    }
    atomicAdd(&sum[c], s);
    atomicAdd(&sumsq[c], q);
}

// ---------------------------------------------------------------- column stats for [N,40]
__global__ __launch_bounds__(256) void stats_out(const float* __restrict__ H, int total,
                                                 float* __restrict__ sum, float* __restrict__ sumsq) {
    __shared__ float ls[D_OUT], lq[D_OUT];
    if (threadIdx.x < D_OUT) { ls[threadIdx.x] = 0.f; lq[threadIdx.x] = 0.f; }
    __syncthreads();
    int stride = gridDim.x * blockDim.x;
    for (int i = blockIdx.x * blockDim.x + threadIdx.x; i < total; i += stride) {
        float v = H[i];
        int c = i % D_OUT;
        atomicAdd(&ls[c], v);
        atomicAdd(&lq[c], v * v);
    }
    __syncthreads();
    if (threadIdx.x < D_OUT) {
        atomicAdd(&sum[threadIdx.x], ls[threadIdx.x]);
        atomicAdd(&sumsq[threadIdx.x], lq[threadIdx.x]);
    }
}

// ---------------------------------------------------------------- GEMM2 fused: z = relu(bn1(hpre)) @ W2 ; BN params from raw sums
__global__ __launch_bounds__(256) void gemm2f(const float* __restrict__ A, const float* __restrict__ W,
                                              const float* __restrict__ colsum, const float* __restrict__ colsumsq,
                                              const float* __restrict__ gamma, const float* __restrict__ beta,
                                              float invN, float* __restrict__ Z, int N) {
    __shared__ float At[64][33];
    __shared__ float Bt[32][D_OUT];
    __shared__ float sc_l[D_HID], sh_l[D_HID];
    int tid = threadIdx.x;
    {   // finalize BN1 stats in-block (256 cols, one per thread)
        float m = colsum[tid] * invN;
        float var = colsumsq[tid] * invN - m * m;
        float rstd = rsqrtf(var + BN_EPS);
        float sc = rstd * gamma[tid];
        sc_l[tid] = sc;
        sh_l[tid] = beta[tid] - m * sc;
    }
    int r0 = blockIdx.x * 64;
    int row = tid & 63;
    int cg  = tid >> 6;
    float acc[10];
    #pragma unroll
    for (int j = 0; j < 10; ++j) acc[j] = 0.f;
    __syncthreads();

    for (int k0 = 0; k0 < D_HID; k0 += 32) {
        #pragma unroll
        for (int i = 0; i < 2; ++i) {
            int idx = i * 256 + tid;
            int r = idx >> 3, kk4 = idx & 7;
            int kb = k0 + kk4 * 4;
            float4 v = make_float4(0.f, 0.f, 0.f, 0.f);
            if (r0 + r < N)
                v = *(const float4*)(A + (size_t)(r0 + r) * D_HID + kb);
            At[r][kk4 * 4 + 0] = fmaxf(v.x * sc_l[kb + 0] + sh_l[kb + 0], 0.f);
            At[r][kk4 * 4 + 1] = fmaxf(v.y * sc_l[kb + 1] + sh_l[kb + 1], 0.f);
            At[r][kk4 * 4 + 2] = fmaxf(v.z * sc_l[kb + 2] + sh_l[kb + 2], 0.f);
            At[r][kk4 * 4 + 3] = fmaxf(v.w * sc_l[kb + 3] + sh_l[kb + 3], 0.f);
        }
        #pragma unroll
        for (int i = 0; i < 5; ++i) {
            int idx = i * 256 + tid;
            int kk = idx / D_OUT, c = idx - kk * D_OUT;
            Bt[kk][c] = W[(size_t)(k0 + kk) * D_OUT + c];
        }
        __syncthreads();
        #pragma unroll
        for (int kk = 0; kk < 32; ++kk) {
            float a = At[row][kk];
            #pragma unroll
            for (int j = 0; j < 10; ++j)
                acc[j] += a * Bt[kk][cg * 10 + j];
        }
        __syncthreads();
    }
    if (r0 + row < N) {
        float* out = Z + (size_t)(r0 + row) * D_OUT + cg * 10;
        #pragma unroll
        for (int j = 0; j < 10; ++j)
            out[j] = acc[j];
    }
}

// ---------------------------------------------------------------- BN2 + log_softmax; BN params from raw sums
__global__ __launch_bounds__(256) void bn_logsoftmax(const float* __restrict__ H,
                                                     const float* __restrict__ colsum, const float* __restrict__ colsumsq,
                                                     const float* __restrict__ gamma, const float* __restrict__ beta,
                                                     float invN, float* __restrict__ out, int N) {
    __shared__ float buf[256 * 41];
    __shared__ float scl[D_OUT], shl[D_OUT];
    int tid = threadIdx.x;
    if (tid < D_OUT) {
        float m = colsum[tid] * invN;
        float var = colsumsq[tid] * invN - m * m;
        float rstd = rsqrtf(var + BN_EPS);
        float sc = rstd * gamma[tid];
        scl[tid] = sc;
        shl[tid] = beta[tid] - m * sc;
    }
    int r0 = blockIdx.x * 256;
    int nrow = min(256, N - r0);
    int total = nrow * D_OUT;
    __syncthreads();
    for (int i = tid; i < total; i += 256)
        buf[i + i / D_OUT] = H[(size_t)r0 * D_OUT + i];
    __syncthreads();
    if (tid < nrow) {
        int base = tid * 41;
        float m = -1e30f;
        #pragma unroll
        for (int j = 0; j < D_OUT; ++j) {
            float v = buf[base + j] * scl[j] + shl[j];
            buf[base + j] = v;
            m = fmaxf(m, v);
        }
        float s = 0.f;
        #pragma unroll
        for (int j = 0; j < D_OUT; ++j)
            s += expf(buf[base + j] - m);
        float lse = m + logf(s);
        #pragma unroll
        for (int j = 0; j < D_OUT; ++j)
            buf[base + j] -= lse;
    }
    __syncthreads();
    for (int i = tid; i < total; i += 256)
        out[(size_t)r0 * D_OUT + i] = buf[i + i / D_OUT];
}

// =================================================================
extern "C" void kernel_launch(void* const* d_in, const int* in_sizes, int n_in,
                              void* d_out, int out_size, void* d_ws, size_t ws_size,
                              hipStream_t stream) {
    const float* x      = (const float*)d_in[0];
    const int*   ei     = (const int*)d_in[1];
    const float* W1     = (const float*)d_in[2];
    const float* b1     = (const float*)d_in[3];
    const float* W2     = (const float*)d_in[4];
    const float* b2     = (const float*)d_in[5];
    const float* gamma1 = (const float*)d_in[6];
    const float* beta1  = (const float*)d_in[7];
    const float* gamma2 = (const float*)d_in[8];
    const float* beta2  = (const float*)d_in[9];
    float* out = (float*)d_out;

    const int N = in_sizes[0] / D_IN;      // 50000
    const int E = in_sizes[1] / 2;         // 800000
    const int* src = ei;
    const int* dst = ei + E;
    const int nb = (N + SCAN_CHUNK - 1) / SCAN_CHUNK;   // 98 <= 128

    // ---------------- workspace layout ----------------
    float* ws = (float*)d_ws;
    float* reg1 = ws;                                   // N*100  (agg1)
    float* hpre = reg1 + (size_t)N * D_IN;              // N*256
    float* z    = hpre + (size_t)N * D_HID;             // N*40
    float* h2   = z    + (size_t)N * D_OUT;             // N*40
    float* stats = h2 + (size_t)N * D_OUT;              // 640 used
    float* colsum1   = stats + 0;     // 256
    float* colsumsq1 = stats + 256;   // 256
    float* colsum2   = stats + 512;   // 40 (pad 64)
    float* colsumsq2 = stats + 576;   // 40 (pad 64)
    int* rp     = (int*)(stats + 640);    // N+1
    int* cursor = rp + N + 1;             // N
    int* bsum   = cursor + N;             // nb (pad 128)
    int* csr    = bsum + 128;             // E

    hipMemsetAsync(stats, 0, 640 * sizeof(float), stream);
    hipMemsetAsync(cursor, 0, (size_t)N * sizeof(int), stream);

    // ---------------- CSR build (shared by both layers) ----------------
    hist_dst<<<1024, 256, 0, stream>>>(dst, cursor, E);
    scan_blocksums<<<nb, 256, 0, stream>>>(cursor, bsum, N);
    scan_bsums<<<1, 128, 0, stream>>>(bsum, nb, rp, N);
    scan_final<<<nb, 256, 0, stream>>>(cursor, bsum, rp, cursor, N);
    fill_csr<<<1024, 256, 0, stream>>>(src, dst, cursor, csr, E);

    // ---------------- layer 1: gather(100) -> gemm1 -> stats ----------------
    gather_rows<25, false><<<(N * 25 + 255) / 256, 256, 0, stream>>>(x, rp, csr, nullptr, reg1, N);
    gemm1<<<dim3((N + 63) / 64, D_HID / 64), 256, 0, stream>>>(reg1, W1, b1, hpre, N);
    stats_hid<<<512, 256, 0, stream>>>(hpre, N, colsum1, colsumsq1);

    // ---------------- layer 2: project first (BN1 finalize + relu fused), then gather(40) ----------------
    gemm2f<<<(N + 63) / 64, 256, 0, stream>>>(hpre, W2, colsum1, colsumsq1, gamma1, beta1, 1.0f / N, z, N);
    gather_rows<10, true><<<(N * 10 + 255) / 256, 256, 0, stream>>>(z, rp, csr, b2, h2, N);
    stats_out<<<1024, 256, 0, stream>>>(h2, N * D_OUT, colsum2, colsumsq2);

    // ---------------- BN2 (finalize fused) + log_softmax ----------------
    bn_logsoftmax<<<(N + 255) / 256, 256, 0, stream>>>(h2, colsum2, colsumsq2, gamma2, beta2, 1.0f / N, out, N);
}

// Round 6
// 309.852 us; speedup vs baseline: 3.1069x; 1.2926x over previous
//
#include <hip/hip_runtime.h>
#include <hip/hip_bf16.h>

#define D_IN   100
#define D_HID  256
#define D_OUT  40
#define BN_EPS 1e-5f
#define SCAN_CHUNK 512

typedef short bf16x8 __attribute__((ext_vector_type(8)));
typedef float f32x4  __attribute__((ext_vector_type(4)));

__device__ inline float b2f(unsigned short u) {
    unsigned int x = ((unsigned int)u) << 16;
    return __builtin_bit_cast(float, x);
}
__device__ inline unsigned short f2b(float f) {
    unsigned int x = __builtin_bit_cast(unsigned int, f);
    unsigned int r = (x + 0x7fffu + ((x >> 16) & 1u)) >> 16;
    return (unsigned short)r;
}

// ---------------------------------------------------------------- CSR build
__global__ void hist_dst(const int* __restrict__ dst, int* __restrict__ cnt, int E) {
    int stride = gridDim.x * blockDim.x;
    for (int i = blockIdx.x * blockDim.x + threadIdx.x; i < E; i += stride)
        atomicAdd(&cnt[dst[i]], 1);
}

__global__ __launch_bounds__(256) void scan_blocksums(const int* __restrict__ cnt,
                                                      int* __restrict__ bsum, int N) {
    __shared__ int red[256];
    int i0 = blockIdx.x * SCAN_CHUNK + threadIdx.x * 2;
    int s = 0;
    if (i0 < N)     s += cnt[i0];
    if (i0 + 1 < N) s += cnt[i0 + 1];
    red[threadIdx.x] = s;
    __syncthreads();
    #pragma unroll
    for (int off = 128; off > 0; off >>= 1) {
        if (threadIdx.x < off) red[threadIdx.x] += red[threadIdx.x + off];
        __syncthreads();
    }
    if (threadIdx.x == 0) bsum[blockIdx.x] = red[0];
}

__global__ __launch_bounds__(128) void scan_bsums(int* __restrict__ bsum, int nb,
                                                  int* __restrict__ rp, int N) {
    __shared__ int bufA[128], bufB[128];
    int tid = threadIdx.x;
    int v = (tid < nb) ? bsum[tid] : 0;
    bufA[tid] = v;
    __syncthreads();
    int* in = bufA; int* out = bufB;
    #pragma unroll
    for (int off = 1; off < 128; off <<= 1) {
        out[tid] = (tid >= off) ? (in[tid - off] + in[tid]) : in[tid];
        __syncthreads();
        int* t = in; in = out; out = t;
    }
    if (tid < nb) bsum[tid] = in[tid] - v;
    if (tid == nb - 1) rp[N] = in[tid];
}

__global__ __launch_bounds__(256) void scan_final(const int* __restrict__ cnt,
                                                  const int* __restrict__ boffs,
                                                  int* __restrict__ rp, int* __restrict__ cursor, int N) {
    __shared__ int bufA[256], bufB[256];
    int tid = threadIdx.x;
    int i0 = blockIdx.x * SCAN_CHUNK + tid * 2;
    int a0 = (i0 < N) ? cnt[i0] : 0;
    int a1 = (i0 + 1 < N) ? cnt[i0 + 1] : 0;
    int s = a0 + a1;
    bufA[tid] = s;
    __syncthreads();
    int* in = bufA; int* out = bufB;
    #pragma unroll
    for (int off = 1; off < 256; off <<= 1) {
        out[tid] = (tid >= off) ? (in[tid - off] + in[tid]) : in[tid];
        __syncthreads();
        int* t = in; in = out; out = t;
    }
    int base = boffs[blockIdx.x] + in[tid] - s;
    if (i0 < N)     { rp[i0] = base;          cursor[i0] = base; }
    if (i0 + 1 < N) { rp[i0 + 1] = base + a0; cursor[i0 + 1] = base + a0; }
}

__global__ void fill_csr(const int* __restrict__ src, const int* __restrict__ dst,
                         int* __restrict__ cursor, int* __restrict__ csr, int E) {
    int stride = gridDim.x * blockDim.x;
    for (int i = blockIdx.x * blockDim.x + threadIdx.x; i < E; i += stride) {
        int pos = atomicAdd(&cursor[dst[i]], 1);
        csr[pos] = src[i];
    }
}

// ---------------------------------------------------------------- prep: W1 -> Wt1b [256][128] bf16 (K zero-padded), W2 -> Wt2b [48][256] bf16
__global__ void prep_w(const float* __restrict__ W1, const float* __restrict__ W2,
                       short* __restrict__ Wt1b, short* __restrict__ Wt2b) {
    int bid = blockIdx.x, tid = threadIdx.x;
    if (bid < 16) {
        int t = bid * 256 + tid;              // 4096: n(256) x chunk(16)
        int n = t >> 4, ch = t & 15;
        unsigned short o[8];
        #pragma unroll
        for (int j = 0; j < 8; ++j) {
            int k = ch * 8 + j;
            o[j] = (k < D_IN) ? f2b(W1[(size_t)k * D_HID + n]) : (unsigned short)0;
        }
        *(uint4*)(Wt1b + (size_t)n * 128 + ch * 8) = *(uint4*)o;
    } else {
        int t = (bid - 16) * 256 + tid;       // 1536: n(48) x chunk(32)
        if (t < 48 * 32) {
            int n = t >> 5, ch = t & 31;
            unsigned short o[8];
            #pragma unroll
            for (int j = 0; j < 8; ++j) {
                int k = ch * 8 + j;
                o[j] = (n < D_OUT) ? f2b(W2[(size_t)k * D_OUT + n]) : (unsigned short)0;
            }
            *(uint4*)(Wt2b + (size_t)n * 256 + ch * 8) = *(uint4*)o;
        }
    }
}

// ---------------------------------------------------------------- x [N][100] f32 -> xb [N][128] bf16 zero-padded
__global__ __launch_bounds__(256) void convert_x(const float* __restrict__ X, short* __restrict__ Xb, int N) {
    int t = blockIdx.x * 256 + threadIdx.x;
    int n = t >> 4, c = t & 15;
    if (n >= N) return;
    unsigned short o[8];
    #pragma unroll
    for (int j = 0; j < 8; ++j) {
        int col = c * 8 + j;
        o[j] = (col < D_IN) ? f2b(X[(size_t)n * D_IN + col]) : (unsigned short)0;
    }
    *(uint4*)(Xb + (size_t)n * 128 + c * 8) = *(uint4*)o;
}

// ---------------------------------------------------------------- gather1: aggb[n] = xb[n] + sum_j xb[csr_j]   (bf16 in/out, fp32 accum)
__global__ __launch_bounds__(256) void gather1_bf16(const short* __restrict__ Xb,
        const int* __restrict__ rp, const int* __restrict__ csr,
        short* __restrict__ Ob, int N) {
    int t = blockIdx.x * 256 + threadIdx.x;
    int n = t >> 4, c = t & 15;
    if (n >= N) return;
    const uint4* Xc = (const uint4*)Xb;
    uint4 v = Xc[(size_t)n * 16 + c];
    float acc[8];
    {
        const unsigned short* us = (const unsigned short*)&v;
        #pragma unroll
        for (int j = 0; j < 8; ++j) acc[j] = b2f(us[j]);
    }
    int e0 = rp[n], e1 = rp[n + 1];
    for (int e = e0; e < e1; ++e) {
        int s = csr[e];
        uint4 u = Xc[(size_t)s * 16 + c];
        const unsigned short* us = (const unsigned short*)&u;
        #pragma unroll
        for (int j = 0; j < 8; ++j) acc[j] += b2f(us[j]);
    }
    unsigned short o[8];
    #pragma unroll
    for (int j = 0; j < 8; ++j) o[j] = f2b(acc[j]);
    *(uint4*)(Ob + (size_t)n * 128 + c * 8) = *(uint4*)o;
}

// ---------------------------------------------------------------- GEMM1 (MFMA): hpreb = aggb[N,128] @ W1 + b1  -> bf16 [N][256]
// transposed-operand form: D[n][m], A_op = Wt rows (n), B_op = agg rows (m)
__global__ __launch_bounds__(256) void gemm1_mfma(const short* __restrict__ Ab,
                                                  const short* __restrict__ Wtb,
                                                  const float* __restrict__ bias,
                                                  short* __restrict__ Hb, int N) {
    __shared__ short Al[128 * 136];
    __shared__ short Wl[64 * 136];
    int tid = threadIdx.x;
    int r0 = blockIdx.x * 128;
    int w = tid >> 6, l = tid & 63;
    int r16 = l & 15, g4 = l >> 4;
    int chunk = tid & 15, rbase = tid >> 4;

    // stage A tile [128][128] -> LDS stride 136
    #pragma unroll
    for (int p = 0; p < 8; ++p) {
        int row = p * 16 + rbase;
        int m = r0 + row;
        uint4 v = make_uint4(0, 0, 0, 0);
        if (m < N) v = *(const uint4*)(Ab + (size_t)m * 128 + chunk * 8);
        *(uint4*)(Al + row * 136 + chunk * 8) = v;
    }

    bf16x8 af[2][4];
    #pragma unroll
    for (int ct = 0; ct < 4; ++ct) {
        __syncthreads();                       // A staged (ct=0) / prev compute done
        #pragma unroll
        for (int p = 0; p < 4; ++p) {          // stage Wt col-tile [64][128]
            int row = p * 16 + rbase;
            *(uint4*)(Wl + row * 136 + chunk * 8) =
                *(const uint4*)(Wtb + (size_t)(ct * 64 + row) * 128 + chunk * 8);
        }
        __syncthreads();
        if (ct == 0) {
            #pragma unroll
            for (int s = 0; s < 2; ++s)
                #pragma unroll
                for (int k = 0; k < 4; ++k)
                    af[s][k] = *(bf16x8*)(Al + (w * 32 + s * 16 + r16) * 136 + k * 32 + g4 * 8);
        }
        bf16x8 wf[4][4];
        #pragma unroll
        for (int n = 0; n < 4; ++n)
            #pragma unroll
            for (int k = 0; k < 4; ++k)
                wf[n][k] = *(bf16x8*)(Wl + (n * 16 + r16) * 136 + k * 32 + g4 * 8);
        #pragma unroll
        for (int s = 0; s < 2; ++s) {
            int m = r0 + w * 32 + s * 16 + r16;
            #pragma unroll
            for (int n = 0; n < 4; ++n) {
                f32x4 acc = {0.f, 0.f, 0.f, 0.f};
                #pragma unroll
                for (int k = 0; k < 4; ++k)
                    acc = __builtin_amdgcn_mfma_f32_16x16x32_bf16(wf[n][k], af[s][k], acc, 0, 0, 0);
                int nc = ct * 64 + n * 16 + g4 * 4;
                float4 b4 = *(const float4*)(bias + nc);
                if (m < N) {
                    ushort4 o;
                    o.x = f2b(acc[0] + b4.x);
                    o.y = f2b(acc[1] + b4.y);
                    o.z = f2b(acc[2] + b4.z);
                    o.w = f2b(acc[3] + b4.w);
                    *(ushort4*)(Hb + (size_t)m * 256 + nc) = o;
                }
            }
        }
    }
}

// ---------------------------------------------------------------- column stats for bf16 [N][256]
__global__ __launch_bounds__(256) void stats_hid_b(const short* __restrict__ H, int N,
                                                   float* __restrict__ sum, float* __restrict__ sumsq) {
    int c = threadIdx.x;
    const unsigned short* Hu = (const unsigned short*)H;
    float s = 0.f, q = 0.f;
    for (int r = blockIdx.x; r < N; r += gridDim.x) {
        float v = b2f(Hu[(size_t)r * 256 + c]);
        s += v; q += v * v;
    }
    atomicAdd(&sum[c], s);
    atomicAdd(&sumsq[c], q);
}

// ---------------------------------------------------------------- GEMM2 (MFMA): z = relu(bn1(hpreb)) @ W2 -> f32 [N][40]
__global__ __launch_bounds__(256) void gemm2_mfma(const short* __restrict__ Hb,
                                                  const short* __restrict__ Wtb,
                                                  const float* __restrict__ colsum, const float* __restrict__ colsumsq,
                                                  const float* __restrict__ gamma, const float* __restrict__ beta,
                                                  float invN, float* __restrict__ Z, int N) {
    __shared__ short Al[128 * 136];
    __shared__ short Wl[48 * 136];
    __shared__ float scl[D_HID], shl[D_HID];
    int tid = threadIdx.x;
    {
        float m = colsum[tid] * invN;
        float var = colsumsq[tid] * invN - m * m;
        float rstd = rsqrtf(var + BN_EPS);
        float sc = rstd * gamma[tid];
        scl[tid] = sc;
        shl[tid] = beta[tid] - m * sc;
    }
    int r0 = blockIdx.x * 128;
    int w = tid >> 6, l = tid & 63;
    int r16 = l & 15, g4 = l >> 4;
    int chunk = tid & 15, rbase = tid >> 4;
    f32x4 acc[2][3];
    #pragma unroll
    for (int s = 0; s < 2; ++s)
        #pragma unroll
        for (int n = 0; n < 3; ++n)
            acc[s][n] = (f32x4){0.f, 0.f, 0.f, 0.f};

    #pragma unroll
    for (int h = 0; h < 2; ++h) {
        __syncthreads();                       // scl ready (h=0) / prev compute done (h=1)
        int kb = h * 128;
        #pragma unroll
        for (int p = 0; p < 8; ++p) {          // stage A half with BN+ReLU
            int row = p * 16 + rbase;
            int m = r0 + row;
            uint4 v = make_uint4(0, 0, 0, 0);
            if (m < N) v = *(const uint4*)(Hb + (size_t)m * 256 + kb + chunk * 8);
            unsigned short* us = (unsigned short*)&v;
            #pragma unroll
            for (int j = 0; j < 8; ++j) {
                int k = kb + chunk * 8 + j;
                float f = b2f(us[j]);
                f = fmaxf(f * scl[k] + shl[k], 0.f);
                us[j] = f2b(f);
            }
            *(uint4*)(Al + row * 136 + chunk * 8) = v;
        }
        #pragma unroll
        for (int p = 0; p < 3; ++p) {          // stage Wt2 half [48][128]
            int row = p * 16 + rbase;
            *(uint4*)(Wl + row * 136 + chunk * 8) =
                *(const uint4*)(Wtb + (size_t)row * 256 + kb + chunk * 8);
        }
        __syncthreads();
        bf16x8 wf[3][4];
        #pragma unroll
        for (int n = 0; n < 3; ++n)
            #pragma unroll
            for (int k = 0; k < 4; ++k)
                wf[n][k] = *(bf16x8*)(Wl + (n * 16 + r16) * 136 + k * 32 + g4 * 8);
        #pragma unroll
        for (int s = 0; s < 2; ++s) {
            #pragma unroll
            for (int k = 0; k < 4; ++k) {
                bf16x8 af = *(bf16x8*)(Al + (w * 32 + s * 16 + r16) * 136 + k * 32 + g4 * 8);
                #pragma unroll
                for (int n = 0; n < 3; ++n)
                    acc[s][n] = __builtin_amdgcn_mfma_f32_16x16x32_bf16(wf[n][k], af, acc[s][n], 0, 0, 0);
            }
        }
    }
    #pragma unroll
    for (int s = 0; s < 2; ++s) {
        int m = r0 + w * 32 + s * 16 + r16;
        if (m >= N) continue;
        #pragma unroll
        for (int n = 0; n < 3; ++n) {
            int nc = n * 16 + g4 * 4;
            if (nc < D_OUT) {
                float4 o = make_float4(acc[s][n][0], acc[s][n][1], acc[s][n][2], acc[s][n][3]);
                *(float4*)(Z + (size_t)m * D_OUT + nc) = o;
            }
        }
    }
}

// ---------------------------------------------------------------- gather2 + fused column stats: h2[n] = z[n] + sum_j z[csr_j] + b2
__global__ __launch_bounds__(256) void gather2_stats(const float* __restrict__ Zin,
        const int* __restrict__ rp, const int* __restrict__ csr,
        const float* __restrict__ bias, float* __restrict__ H2,
        float* __restrict__ gsum, float* __restrict__ gsumsq, int N) {
    __shared__ float ls[D_OUT], lq[D_OUT];
    int tid = threadIdx.x;
    if (tid < D_OUT) { ls[tid] = 0.f; lq[tid] = 0.f; }
    __syncthreads();
    int t = blockIdx.x * 256 + tid;
    int n = t / 10, c = t - n * 10;
    if (n < N) {
        const float4* Xc = (const float4*)Zin + c;
        float4 acc = Xc[(size_t)n * 10];
        int e0 = rp[n], e1 = rp[n + 1];
        for (int e = e0; e < e1; ++e) {
            int s = csr[e];
            float4 u = Xc[(size_t)s * 10];
            acc.x += u.x; acc.y += u.y; acc.z += u.z; acc.w += u.w;
        }
        float4 b = ((const float4*)bias)[c];
        acc.x += b.x; acc.y += b.y; acc.z += b.z; acc.w += b.w;
        ((float4*)H2)[(size_t)n * 10 + c] = acc;
        int cc = c * 4;
        atomicAdd(&ls[cc + 0], acc.x); atomicAdd(&lq[cc + 0], acc.x * acc.x);
        atomicAdd(&ls[cc + 1], acc.y); atomicAdd(&lq[cc + 1], acc.y * acc.y);
        atomicAdd(&ls[cc + 2], acc.z); atomicAdd(&lq[cc + 2], acc.z * acc.z);
        atomicAdd(&ls[cc + 3], acc.w); atomicAdd(&lq[cc + 3], acc.w * acc.w);
    }
    __syncthreads();
    if (tid < D_OUT) {
        atomicAdd(&gsum[tid], ls[tid]);
        atomicAdd(&gsumsq[tid], lq[tid]);
    }
}

// ---------------------------------------------------------------- BN2 + log_softmax; BN params from raw sums
__global__ __launch_bounds__(256) void bn_logsoftmax(const float* __restrict__ H,
                                                     const float* __restrict__ colsum, const float* __restrict__ colsumsq,
                                                     const float* __restrict__ gamma, const float* __restrict__ beta,
                                                     float invN, float* __restrict__ out, int N) {
    __shared__ float buf[256 * 41];
    __shared__ float scl[D_OUT], shl[D_OUT];
    int tid = threadIdx.x;
    if (tid < D_OUT) {
        float m = colsum[tid] * invN;
        float var = colsumsq[tid] * invN - m * m;
        float rstd = rsqrtf(var + BN_EPS);
        float sc = rstd * gamma[tid];
        scl[tid] = sc;
        shl[tid] = beta[tid] - m * sc;
    }
    int r0 = blockIdx.x * 256;
    int nrow = min(256, N - r0);
    int total = nrow * D_OUT;
    __syncthreads();
    for (int i = tid; i < total; i += 256)
        buf[i + i / D_OUT] = H[(size_t)r0 * D_OUT + i];
    __syncthreads();
    if (tid < nrow) {
        int base = tid * 41;
        float m = -1e30f;
        #pragma unroll
        for (int j = 0; j < D_OUT; ++j) {
            float v = buf[base + j] * scl[j] + shl[j];
            buf[base + j] = v;
            m = fmaxf(m, v);
        }
        float s = 0.f;
        #pragma unroll
        for (int j = 0; j < D_OUT; ++j)
            s += expf(buf[base + j] - m);
        float lse = m + logf(s);
        #pragma unroll
        for (int j = 0; j < D_OUT; ++j)
            buf[base + j] -= lse;
    }
    __syncthreads();
    for (int i = tid; i < total; i += 256)
        out[(size_t)r0 * D_OUT + i] = buf[i + i / D_OUT];
}

// =================================================================
extern "C" void kernel_launch(void* const* d_in, const int* in_sizes, int n_in,
                              void* d_out, int out_size, void* d_ws, size_t ws_size,
                              hipStream_t stream) {
    const float* x      = (const float*)d_in[0];
    const int*   ei     = (const int*)d_in[1];
    const float* W1     = (const float*)d_in[2];
    const float* b1     = (const float*)d_in[3];
    const float* W2     = (const float*)d_in[4];
    const float* b2     = (const float*)d_in[5];
    const float* gamma1 = (const float*)d_in[6];
    const float* beta1  = (const float*)d_in[7];
    const float* gamma2 = (const float*)d_in[8];
    const float* beta2  = (const float*)d_in[9];
    float* out = (float*)d_out;

    const int N = in_sizes[0] / D_IN;      // 50000
    const int E = in_sizes[1] / 2;         // 800000
    const int* src = ei;
    const int* dst = ei + E;
    const int nb = (N + SCAN_CHUNK - 1) / SCAN_CHUNK;   // 98

    // ---------------- workspace layout ----------------
    short* xb    = (short*)d_ws;                       // N*128 bf16
    short* aggb  = xb + (size_t)N * 128;               // N*128 bf16
    short* hpreb = aggb + (size_t)N * 128;             // N*256 bf16
    short* Wt1b  = hpreb + (size_t)N * 256;            // 256*128 bf16
    short* Wt2b  = Wt1b + 256 * 128;                   // 48*256 bf16
    float* z     = (float*)(Wt2b + 48 * 256);          // N*40 f32
    float* h2    = z + (size_t)N * D_OUT;              // N*40 f32
    float* stats = h2 + (size_t)N * D_OUT;             // 640 f32
    float* colsum1   = stats + 0;     // 256
    float* colsumsq1 = stats + 256;   // 256
    float* colsum2   = stats + 512;   // 40 (pad 64)
    float* colsumsq2 = stats + 576;   // 40 (pad 64)
    int* rp     = (int*)(stats + 640);    // N+1
    int* cursor = rp + N + 1;             // N
    int* bsum   = cursor + N;             // pad 128
    int* csr    = bsum + 128;             // E

    hipMemsetAsync(stats, 0, 640 * sizeof(float), stream);
    hipMemsetAsync(cursor, 0, (size_t)N * sizeof(int), stream);

    // ---------------- prep + CSR ----------------
    prep_w<<<22, 256, 0, stream>>>(W1, W2, Wt1b, Wt2b);
    convert_x<<<(N * 16 + 255) / 256, 256, 0, stream>>>(x, xb, N);
    hist_dst<<<1024, 256, 0, stream>>>(dst, cursor, E);
    scan_blocksums<<<nb, 256, 0, stream>>>(cursor, bsum, N);
    scan_bsums<<<1, 128, 0, stream>>>(bsum, nb, rp, N);
    scan_final<<<nb, 256, 0, stream>>>(cursor, bsum, rp, cursor, N);
    fill_csr<<<1024, 256, 0, stream>>>(src, dst, cursor, csr, E);

    // ---------------- layer 1 ----------------
    gather1_bf16<<<(N * 16 + 255) / 256, 256, 0, stream>>>(xb, rp, csr, aggb, N);
    gemm1_mfma<<<(N + 127) / 128, 256, 0, stream>>>(aggb, Wt1b, b1, hpreb, N);
    stats_hid_b<<<512, 256, 0, stream>>>(hpreb, N, colsum1, colsumsq1);

    // ---------------- layer 2 ----------------
    gemm2_mfma<<<(N + 127) / 128, 256, 0, stream>>>(hpreb, Wt2b, colsum1, colsumsq1,
                                                    gamma1, beta1, 1.0f / N, z, N);
    gather2_stats<<<(N * 10 + 255) / 256, 256, 0, stream>>>(z, rp, csr, b2, h2,
                                                            colsum2, colsumsq2, N);

    // ---------------- BN2 + log_softmax ----------------
    bn_logsoftmax<<<(N + 255) / 256, 256, 0, stream>>>(h2, colsum2, colsumsq2,
                                                       gamma2, beta2, 1.0f / N, out, N);
}

// Round 7
// 251.674 us; speedup vs baseline: 3.8251x; 1.2312x over previous
//
#include <hip/hip_runtime.h>
#include <hip/hip_bf16.h>

#define D_IN   100
#define D_HID  256
#define D_OUT  40
#define BN_EPS 1e-5f
#define BSHIFT 8          // coarse bucket = dst >> 8  (256 dsts/bucket)
#define P2_EPB 2048       // edges per block in partition pass
#define P3_CAP 6144       // LDS pair capacity in build_csr (mean ~4096)

typedef short bf16x8 __attribute__((ext_vector_type(8)));
typedef float f32x4  __attribute__((ext_vector_type(4)));

__device__ inline float b2f(unsigned short u) {
    unsigned int x = ((unsigned int)u) << 16;
    return __builtin_bit_cast(float, x);
}
__device__ inline unsigned short f2b(float f) {
    unsigned int x = __builtin_bit_cast(unsigned int, f);
    unsigned int r = (x + 0x7fffu + ((x >> 16) & 1u)) >> 16;
    return (unsigned short)r;
}

// ================================================================ CSR build (binned, coalesced)
// P0: coarse bucket histogram
__global__ __launch_bounds__(256) void bucket_hist(const int* __restrict__ dst,
                                                   int* __restrict__ bcnt, int E) {
    __shared__ int h[256];
    int tid = threadIdx.x;
    h[tid] = 0;
    __syncthreads();
    int stride = gridDim.x * blockDim.x;
    for (int i = blockIdx.x * blockDim.x + tid; i < E; i += stride)
        atomicAdd(&h[dst[i] >> BSHIFT], 1);
    __syncthreads();
    if (h[tid]) atomicAdd(&bcnt[tid], h[tid]);
}

// P1: scan bucket counts -> bbase (exclusive), init bcursor, rp[N]=E
__global__ __launch_bounds__(256) void bucket_scan(const int* __restrict__ bcnt,
        int* __restrict__ bbase, int* __restrict__ bcursor, int* __restrict__ rp,
        int NB, int N, int E) {
    __shared__ int A[256], B[256];
    int tid = threadIdx.x;
    int v = (tid < NB) ? bcnt[tid] : 0;
    A[tid] = v;
    __syncthreads();
    int* in = A; int* out = B;
    #pragma unroll
    for (int off = 1; off < 256; off <<= 1) {
        out[tid] = (tid >= off) ? (in[tid - off] + in[tid]) : in[tid];
        __syncthreads();
        int* t = in; in = out; out = t;
    }
    int excl = in[tid] - v;
    if (tid < NB) { bbase[tid] = excl; bcursor[tid] = excl; }
    if (tid == 0) { bbase[NB] = E; rp[N] = E; }
}

// P2: partition edges into bucket-grouped (src,dst) pairs, burst-coalesced writes
__global__ __launch_bounds__(256) void partition_edges(const int* __restrict__ src,
        const int* __restrict__ dst, int* __restrict__ bcursor,
        uint2* __restrict__ pairs, int E) {
    __shared__ int hist[256];
    __shared__ int lbase[256];
    __shared__ int rbase[256];
    __shared__ int sA[256], sB[256];
    __shared__ uint2 st[P2_EPB];
    int tid = threadIdx.x;
    int base = blockIdx.x * P2_EPB;
    hist[tid] = 0;
    __syncthreads();
    int s[8], d[8], lo[8];
    #pragma unroll
    for (int p = 0; p < 8; ++p) {
        int i = base + p * 256 + tid;
        if (i < E) {
            s[p] = src[i]; d[p] = dst[i];
            lo[p] = atomicAdd(&hist[d[p] >> BSHIFT], 1);
        } else d[p] = -1;
    }
    __syncthreads();
    int v = hist[tid];
    sA[tid] = v;
    __syncthreads();
    int* in = sA; int* out = sB;
    #pragma unroll
    for (int off = 1; off < 256; off <<= 1) {
        out[tid] = (tid >= off) ? (in[tid - off] + in[tid]) : in[tid];
        __syncthreads();
        int* t = in; in = out; out = t;
    }
    lbase[tid] = in[tid] - v;
    if (v > 0) rbase[tid] = atomicAdd(&bcursor[tid], v);
    __syncthreads();
    #pragma unroll
    for (int p = 0; p < 8; ++p)
        if (d[p] >= 0)
            st[lbase[d[p] >> BSHIFT] + lo[p]] = make_uint2((unsigned)s[p], (unsigned)d[p]);
    __syncthreads();
    int cnt_total = min(P2_EPB, E - base);
    for (int i = tid; i < cnt_total; i += 256) {
        uint2 pr = st[i];
        int b = (int)(pr.y >> BSHIFT);
        pairs[rbase[b] + (i - lbase[b])] = pr;
    }
}

// P3: per-bucket fine CSR build; writes rp + ordered csr, all coalesced
__global__ __launch_bounds__(256) void build_csr(const uint2* __restrict__ pairs,
        const int* __restrict__ bbase, int* __restrict__ rp, int* __restrict__ csr, int N) {
    __shared__ int hist[256];
    __shared__ int cur[256];
    __shared__ int sA[256], sB[256];
    __shared__ int ordered[P3_CAP];
    int tid = threadIdx.x;
    int b = blockIdx.x;
    int p0 = bbase[b], p1 = bbase[b + 1];
    int cnt = p1 - p0;
    hist[tid] = 0;
    __syncthreads();
    for (int i = tid; i < cnt; i += 256)
        atomicAdd(&hist[pairs[p0 + i].y & 255], 1);
    __syncthreads();
    int v = hist[tid];
    sA[tid] = v;
    __syncthreads();
    int* in = sA; int* out = sB;
    #pragma unroll
    for (int off = 1; off < 256; off <<= 1) {
        out[tid] = (tid >= off) ? (in[tid - off] + in[tid]) : in[tid];
        __syncthreads();
        int* t = in; in = out; out = t;
    }
    int excl = in[tid] - v;
    int dg = (b << BSHIFT) + tid;
    if (dg < N) rp[dg] = p0 + excl;
    cur[tid] = excl;
    __syncthreads();
    if (cnt <= P3_CAP) {
        for (int i = tid; i < cnt; i += 256) {
            uint2 pr = pairs[p0 + i];
            int off = atomicAdd(&cur[pr.y & 255], 1);
            ordered[off] = (int)pr.x;
        }
        __syncthreads();
        for (int i = tid; i < cnt; i += 256)
            csr[p0 + i] = ordered[i];
    } else {   // fallback: direct scatter, still block-private L2-local region
        for (int i = tid; i < cnt; i += 256) {
            uint2 pr = pairs[p0 + i];
            int off = atomicAdd(&cur[pr.y & 255], 1);
            csr[p0 + off] = (int)pr.x;
        }
    }
}

// ================================================================ prep
__global__ void prep_w(const float* __restrict__ W1, const float* __restrict__ W2,
                       short* __restrict__ Wt1b, short* __restrict__ Wt2b) {
    int bid = blockIdx.x, tid = threadIdx.x;
    if (bid < 16) {
        int t = bid * 256 + tid;              // 4096: n(256) x chunk(16)
        int n = t >> 4, ch = t & 15;
        unsigned short o[8];
        #pragma unroll
        for (int j = 0; j < 8; ++j) {
            int k = ch * 8 + j;
            o[j] = (k < D_IN) ? f2b(W1[(size_t)k * D_HID + n]) : (unsigned short)0;
        }
        *(uint4*)(Wt1b + (size_t)n * 128 + ch * 8) = *(uint4*)o;
    } else {
        int t = (bid - 16) * 256 + tid;       // 1536: n(48) x chunk(32)
        if (t < 48 * 32) {
            int n = t >> 5, ch = t & 31;
            unsigned short o[8];
            #pragma unroll
            for (int j = 0; j < 8; ++j) {
                int k = ch * 8 + j;
                o[j] = (n < D_OUT) ? f2b(W2[(size_t)k * D_OUT + n]) : (unsigned short)0;
            }
            *(uint4*)(Wt2b + (size_t)n * 256 + ch * 8) = *(uint4*)o;
        }
    }
}

__global__ __launch_bounds__(256) void convert_x(const float* __restrict__ X, short* __restrict__ Xb, int N) {
    int t = blockIdx.x * 256 + threadIdx.x;
    int n = t >> 4, c = t & 15;
    if (n >= N) return;
    unsigned short o[8];
    #pragma unroll
    for (int j = 0; j < 8; ++j) {
        int col = c * 8 + j;
        o[j] = (col < D_IN) ? f2b(X[(size_t)n * D_IN + col]) : (unsigned short)0;
    }
    *(uint4*)(Xb + (size_t)n * 128 + c * 8) = *(uint4*)o;
}

// ================================================================ gather1 (bf16, fp32 accum)
__global__ __launch_bounds__(256) void gather1_bf16(const short* __restrict__ Xb,
        const int* __restrict__ rp, const int* __restrict__ csr,
        short* __restrict__ Ob, int N) {
    int t = blockIdx.x * 256 + threadIdx.x;
    int n = t >> 4, c = t & 15;
    if (n >= N) return;
    const uint4* Xc = (const uint4*)Xb;
    uint4 v = Xc[(size_t)n * 16 + c];
    float acc[8];
    {
        const unsigned short* us = (const unsigned short*)&v;
        #pragma unroll
        for (int j = 0; j < 8; ++j) acc[j] = b2f(us[j]);
    }
    int e0 = rp[n], e1 = rp[n + 1];
    for (int e = e0; e < e1; ++e) {
        int s = csr[e];
        uint4 u = Xc[(size_t)s * 16 + c];
        const unsigned short* us = (const unsigned short*)&u;
        #pragma unroll
        for (int j = 0; j < 8; ++j) acc[j] += b2f(us[j]);
    }
    unsigned short o[8];
    #pragma unroll
    for (int j = 0; j < 8; ++j) o[j] = f2b(acc[j]);
    *(uint4*)(Ob + (size_t)n * 128 + c * 8) = *(uint4*)o;
}

// ================================================================ GEMM1 (MFMA): hpreb = aggb[N,128] @ W1 + b1 -> bf16 [N][256]
__global__ __launch_bounds__(256) void gemm1_mfma(const short* __restrict__ Ab,
                                                  const short* __restrict__ Wtb,
                                                  const float* __restrict__ bias,
                                                  short* __restrict__ Hb, int N) {
    __shared__ short Al[128 * 136];
    __shared__ short Wl[64 * 136];
    int tid = threadIdx.x;
    int r0 = blockIdx.x * 128;
    int w = tid >> 6, l = tid & 63;
    int r16 = l & 15, g4 = l >> 4;
    int chunk = tid & 15, rbase = tid >> 4;

    #pragma unroll
    for (int p = 0; p < 8; ++p) {
        int row = p * 16 + rbase;
        int m = r0 + row;
        uint4 v = make_uint4(0, 0, 0, 0);
        if (m < N) v = *(const uint4*)(Ab + (size_t)m * 128 + chunk * 8);
        *(uint4*)(Al + row * 136 + chunk * 8) = v;
    }

    bf16x8 af[2][4];
    #pragma unroll
    for (int ct = 0; ct < 4; ++ct) {
        __syncthreads();
        #pragma unroll
        for (int p = 0; p < 4; ++p) {
            int row = p * 16 + rbase;
            *(uint4*)(Wl + row * 136 + chunk * 8) =
                *(const uint4*)(Wtb + (size_t)(ct * 64 + row) * 128 + chunk * 8);
        }
        __syncthreads();
        if (ct == 0) {
            #pragma unroll
            for (int s = 0; s < 2; ++s)
                #pragma unroll
                for (int k = 0; k < 4; ++k)
                    af[s][k] = *(bf16x8*)(Al + (w * 32 + s * 16 + r16) * 136 + k * 32 + g4 * 8);
        }
        bf16x8 wf[4][4];
        #pragma unroll
        for (int n = 0; n < 4; ++n)
            #pragma unroll
            for (int k = 0; k < 4; ++k)
                wf[n][k] = *(bf16x8*)(Wl + (n * 16 + r16) * 136 + k * 32 + g4 * 8);
        #pragma unroll
        for (int s = 0; s < 2; ++s) {
            int m = r0 + w * 32 + s * 16 + r16;
            #pragma unroll
            for (int n = 0; n < 4; ++n) {
                f32x4 acc = {0.f, 0.f, 0.f, 0.f};
                #pragma unroll
                for (int k = 0; k < 4; ++k)
                    acc = __builtin_amdgcn_mfma_f32_16x16x32_bf16(wf[n][k], af[s][k], acc, 0, 0, 0);
                int nc = ct * 64 + n * 16 + g4 * 4;
                float4 b4 = *(const float4*)(bias + nc);
                if (m < N) {
                    ushort4 o;
                    o.x = f2b(acc[0] + b4.x);
                    o.y = f2b(acc[1] + b4.y);
                    o.z = f2b(acc[2] + b4.z);
                    o.w = f2b(acc[3] + b4.w);
                    *(ushort4*)(Hb + (size_t)m * 256 + nc) = o;
                }
            }
        }
    }
}

// ================================================================ column stats bf16 [N][256]
__global__ __launch_bounds__(256) void stats_hid_b(const short* __restrict__ H, int N,
                                                   float* __restrict__ sum, float* __restrict__ sumsq) {
    int c = threadIdx.x;
    const unsigned short* Hu = (const unsigned short*)H;
    float s = 0.f, q = 0.f;
    for (int r = blockIdx.x; r < N; r += gridDim.x) {
        float v = b2f(Hu[(size_t)r * 256 + c]);
        s += v; q += v * v;
    }
    atomicAdd(&sum[c], s);
    atomicAdd(&sumsq[c], q);
}

// ================================================================ GEMM2 (MFMA): z = relu(bn1(hpreb)) @ W2 -> f32 [N][40]
__global__ __launch_bounds__(256) void gemm2_mfma(const short* __restrict__ Hb,
                                                  const short* __restrict__ Wtb,
                                                  const float* __restrict__ colsum, const float* __restrict__ colsumsq,
                                                  const float* __restrict__ gamma, const float* __restrict__ beta,
                                                  float invN, float* __restrict__ Z, int N) {
    __shared__ short Al[128 * 136];
    __shared__ short Wl[48 * 136];
    __shared__ float scl[D_HID], shl[D_HID];
    int tid = threadIdx.x;
    {
        float m = colsum[tid] * invN;
        float var = colsumsq[tid] * invN - m * m;
        float rstd = rsqrtf(var + BN_EPS);
        float sc = rstd * gamma[tid];
        scl[tid] = sc;
        shl[tid] = beta[tid] - m * sc;
    }
    int r0 = blockIdx.x * 128;
    int w = tid >> 6, l = tid & 63;
    int r16 = l & 15, g4 = l >> 4;
    int chunk = tid & 15, rbase = tid >> 4;
    f32x4 acc[2][3];
    #pragma unroll
    for (int s = 0; s < 2; ++s)
        #pragma unroll
        for (int n = 0; n < 3; ++n)
            acc[s][n] = (f32x4){0.f, 0.f, 0.f, 0.f};

    #pragma unroll
    for (int h = 0; h < 2; ++h) {
        __syncthreads();
        int kb = h * 128;
        #pragma unroll
        for (int p = 0; p < 8; ++p) {
            int row = p * 16 + rbase;
            int m = r0 + row;
            uint4 v = make_uint4(0, 0, 0, 0);
            if (m < N) v = *(const uint4*)(Hb + (size_t)m * 256 + kb + chunk * 8);
            unsigned short* us = (unsigned short*)&v;
            #pragma unroll
            for (int j = 0; j < 8; ++j) {
                int k = kb + chunk * 8 + j;
                float f = b2f(us[j]);
                f = fmaxf(f * scl[k] + shl[k], 0.f);
                us[j] = f2b(f);
            }
            *(uint4*)(Al + row * 136 + chunk * 8) = v;
        }
        #pragma unroll
        for (int p = 0; p < 3; ++p) {
            int row = p * 16 + rbase;
            *(uint4*)(Wl + row * 136 + chunk * 8) =
                *(const uint4*)(Wtb + (size_t)row * 256 + kb + chunk * 8);
        }
        __syncthreads();
        bf16x8 wf[3][4];
        #pragma unroll
        for (int n = 0; n < 3; ++n)
            #pragma unroll
            for (int k = 0; k < 4; ++k)
                wf[n][k] = *(bf16x8*)(Wl + (n * 16 + r16) * 136 + k * 32 + g4 * 8);
        #pragma unroll
        for (int s = 0; s < 2; ++s) {
            #pragma unroll
            for (int k = 0; k < 4; ++k) {
                bf16x8 af = *(bf16x8*)(Al + (w * 32 + s * 16 + r16) * 136 + k * 32 + g4 * 8);
                #pragma unroll
                for (int n = 0; n < 3; ++n)
                    acc[s][n] = __builtin_amdgcn_mfma_f32_16x16x32_bf16(wf[n][k], af, acc[s][n], 0, 0, 0);
            }
        }
    }
    #pragma unroll
    for (int s = 0; s < 2; ++s) {
        int m = r0 + w * 32 + s * 16 + r16;
        if (m >= N) continue;
        #pragma unroll
        for (int n = 0; n < 3; ++n) {
            int nc = n * 16 + g4 * 4;
            if (nc < D_OUT) {
                float4 o = make_float4(acc[s][n][0], acc[s][n][1], acc[s][n][2], acc[s][n][3]);
                *(float4*)(Z + (size_t)m * D_OUT + nc) = o;
            }
        }
    }
}

// ================================================================ gather2 + fused column stats
__global__ __launch_bounds__(256) void gather2_stats(const float* __restrict__ Zin,
        const int* __restrict__ rp, const int* __restrict__ csr,
        const float* __restrict__ bias, float* __restrict__ H2,
        float* __restrict__ gsum, float* __restrict__ gsumsq, int N) {
    __shared__ float ls[D_OUT], lq[D_OUT];
    int tid = threadIdx.x;
    if (tid < D_OUT) { ls[tid] = 0.f; lq[tid] = 0.f; }
    __syncthreads();
    int t = blockIdx.x * 256 + tid;
    int n = t / 10, c = t - n * 10;
    if (n < N) {
        const float4* Xc = (const float4*)Zin + c;
        float4 acc = Xc[(size_t)n * 10];
        int e0 = rp[n], e1 = rp[n + 1];
        for (int e = e0; e < e1; ++e) {
            int s = csr[e];
            float4 u = Xc[(size_t)s * 10];
            acc.x += u.x; acc.y += u.y; acc.z += u.z; acc.w += u.w;
        }
        float4 b = ((const float4*)bias)[c];
        acc.x += b.x; acc.y += b.y; acc.z += b.z; acc.w += b.w;
        ((float4*)H2)[(size_t)n * 10 + c] = acc;
        int cc = c * 4;
        atomicAdd(&ls[cc + 0], acc.x); atomicAdd(&lq[cc + 0], acc.x * acc.x);
        atomicAdd(&ls[cc + 1], acc.y); atomicAdd(&lq[cc + 1], acc.y * acc.y);
        atomicAdd(&ls[cc + 2], acc.z); atomicAdd(&lq[cc + 2], acc.z * acc.z);
        atomicAdd(&ls[cc + 3], acc.w); atomicAdd(&lq[cc + 3], acc.w * acc.w);
    }
    __syncthreads();
    if (tid < D_OUT) {
        atomicAdd(&gsum[tid], ls[tid]);
        atomicAdd(&gsumsq[tid], lq[tid]);
    }
}

// ================================================================ BN2 + log_softmax
__global__ __launch_bounds__(256) void bn_logsoftmax(const float* __restrict__ H,
                                                     const float* __restrict__ colsum, const float* __restrict__ colsumsq,
                                                     const float* __restrict__ gamma, const float* __restrict__ beta,
                                                     float invN, float* __restrict__ out, int N) {
    __shared__ float buf[256 * 41];
    __shared__ float scl[D_OUT], shl[D_OUT];
    int tid = threadIdx.x;
    if (tid < D_OUT) {
        float m = colsum[tid] * invN;
        float var = colsumsq[tid] * invN - m * m;
        float rstd = rsqrtf(var + BN_EPS);
        float sc = rstd * gamma[tid];
        scl[tid] = sc;
        shl[tid] = beta[tid] - m * sc;
    }
    int r0 = blockIdx.x * 256;
    int nrow = min(256, N - r0);
    int total = nrow * D_OUT;
    __syncthreads();
    for (int i = tid; i < total; i += 256)
        buf[i + i / D_OUT] = H[(size_t)r0 * D_OUT + i];
    __syncthreads();
    if (tid < nrow) {
        int base = tid * 41;
        float m = -1e30f;
        #pragma unroll
        for (int j = 0; j < D_OUT; ++j) {
            float v = buf[base + j] * scl[j] + shl[j];
            buf[base + j] = v;
            m = fmaxf(m, v);
        }
        float s = 0.f;
        #pragma unroll
        for (int j = 0; j < D_OUT; ++j)
            s += expf(buf[base + j] - m);
        float lse = m + logf(s);
        #pragma unroll
        for (int j = 0; j < D_OUT; ++j)
            buf[base + j] -= lse;
    }
    __syncthreads();
    for (int i = tid; i < total; i += 256)
        out[(size_t)r0 * D_OUT + i] = buf[i + i / D_OUT];
}

// =================================================================
extern "C" void kernel_launch(void* const* d_in, const int* in_sizes, int n_in,
                              void* d_out, int out_size, void* d_ws, size_t ws_size,
                              hipStream_t stream) {
    const float* x      = (const float*)d_in[0];
    const int*   ei     = (const int*)d_in[1];
    const float* W1     = (const float*)d_in[2];
    const float* b1     = (const float*)d_in[3];
    const float* W2     = (const float*)d_in[4];
    const float* b2     = (const float*)d_in[5];
    const float* gamma1 = (const float*)d_in[6];
    const float* beta1  = (const float*)d_in[7];
    const float* gamma2 = (const float*)d_in[8];
    const float* beta2  = (const float*)d_in[9];
    float* out = (float*)d_out;

    const int N = in_sizes[0] / D_IN;      // 50000
    const int E = in_sizes[1] / 2;         // 800000
    const int* src = ei;
    const int* dst = ei + E;
    const int nbk = (N + 255) >> BSHIFT;   // 196 coarse buckets

    // ---------------- workspace layout ----------------
    short* xb    = (short*)d_ws;                       // N*128 bf16
    short* aggb  = xb + (size_t)N * 128;               // N*128 bf16
    short* hpreb = aggb + (size_t)N * 128;             // N*256 bf16
    short* Wt1b  = hpreb + (size_t)N * 256;            // 256*128
    short* Wt2b  = Wt1b + 256 * 128;                   // 48*256
    float* z     = (float*)(Wt2b + 48 * 256);          // N*40 f32
    float* h2    = z + (size_t)N * D_OUT;              // N*40 f32
    float* stats = h2 + (size_t)N * D_OUT;             // 640 f32
    float* colsum1   = stats + 0;     // 256
    float* colsumsq1 = stats + 256;   // 256
    float* colsum2   = stats + 512;   // 40 (pad 64)
    float* colsumsq2 = stats + 576;   // 40 (pad 64)
    int* rp      = (int*)(stats + 640);   // N+1 (pad to N+4 for alignment)
    int* bcnt    = rp + N + 4;            // 256
    int* bbase   = bcnt + 256;            // 260 (NB+1 used)
    int* bcursor = bbase + 260;           // 256
    int* csr     = bcursor + 256;         // E
    uint2* pairs = (uint2*)(csr + E);     // E (8B-aligned by construction)

    hipMemsetAsync(stats, 0, 640 * sizeof(float), stream);
    hipMemsetAsync(bcnt, 0, 256 * sizeof(int), stream);

    // ---------------- prep + CSR build ----------------
    prep_w<<<22, 256, 0, stream>>>(W1, W2, Wt1b, Wt2b);
    convert_x<<<(N * 16 + 255) / 256, 256, 0, stream>>>(x, xb, N);
    bucket_hist<<<512, 256, 0, stream>>>(dst, bcnt, E);
    bucket_scan<<<1, 256, 0, stream>>>(bcnt, bbase, bcursor, rp, nbk, N, E);
    partition_edges<<<(E + P2_EPB - 1) / P2_EPB, 256, 0, stream>>>(src, dst, bcursor, pairs, E);
    build_csr<<<nbk, 256, 0, stream>>>(pairs, bbase, rp, csr, N);

    // ---------------- layer 1 ----------------
    gather1_bf16<<<(N * 16 + 255) / 256, 256, 0, stream>>>(xb, rp, csr, aggb, N);
    gemm1_mfma<<<(N + 127) / 128, 256, 0, stream>>>(aggb, Wt1b, b1, hpreb, N);
    stats_hid_b<<<512, 256, 0, stream>>>(hpreb, N, colsum1, colsumsq1);

    // ---------------- layer 2 ----------------
    gemm2_mfma<<<(N + 127) / 128, 256, 0, stream>>>(hpreb, Wt2b, colsum1, colsumsq1,
                                                    gamma1, beta1, 1.0f / N, z, N);
    gather2_stats<<<(N * 10 + 255) / 256, 256, 0, stream>>>(z, rp, csr, b2, h2,
                                                            colsum2, colsumsq2, N);

    // ---------------- BN2 + log_softmax ----------------
    bn_logsoftmax<<<(N + 255) / 256, 256, 0, stream>>>(h2, colsum2, colsumsq2,
                                                       gamma2, beta2, 1.0f / N, out, N);
}

// Round 8
// 217.240 us; speedup vs baseline: 4.4314x; 1.1585x over previous
//
#include <hip/hip_runtime.h>
#include <hip/hip_bf16.h>

#define D_IN   100
#define D_HID  256
#define D_OUT  40
#define BN_EPS 1e-5f
#define BSHIFT 8
#define P2_EPB 2048
#define P3_CAP 6144

typedef short bf16x8 __attribute__((ext_vector_type(8)));
typedef float f32x4  __attribute__((ext_vector_type(4)));

__device__ inline float b2f(unsigned short u) {
    unsigned int x = ((unsigned int)u) << 16;
    return __builtin_bit_cast(float, x);
}
__device__ inline unsigned short f2b(float f) {
    unsigned int x = __builtin_bit_cast(unsigned int, f);
    unsigned int r = (x + 0x7fffu + ((x >> 16) & 1u)) >> 16;
    return (unsigned short)r;
}

// ================================================================ CSR build (binned, coalesced)
__global__ __launch_bounds__(256) void bucket_hist(const int* __restrict__ dst,
                                                   int* __restrict__ bcnt, int E) {
    __shared__ int h[256];
    int tid = threadIdx.x;
    h[tid] = 0;
    __syncthreads();
    int stride = gridDim.x * blockDim.x;
    for (int i = blockIdx.x * blockDim.x + tid; i < E; i += stride)
        atomicAdd(&h[dst[i] >> BSHIFT], 1);
    __syncthreads();
    if (h[tid]) atomicAdd(&bcnt[tid], h[tid]);
}

__global__ __launch_bounds__(256) void bucket_scan(const int* __restrict__ bcnt,
        int* __restrict__ bbase, int* __restrict__ bcursor, int* __restrict__ rp,
        int NB, int N, int E) {
    __shared__ int A[256], B[256];
    int tid = threadIdx.x;
    int v = (tid < NB) ? bcnt[tid] : 0;
    A[tid] = v;
    __syncthreads();
    int* in = A; int* out = B;
    #pragma unroll
    for (int off = 1; off < 256; off <<= 1) {
        out[tid] = (tid >= off) ? (in[tid - off] + in[tid]) : in[tid];
        __syncthreads();
        int* t = in; in = out; out = t;
    }
    int excl = in[tid] - v;
    if (tid < NB) { bbase[tid] = excl; bcursor[tid] = excl; }
    if (tid == 0) { bbase[NB] = E; rp[N] = E; }
}

__global__ __launch_bounds__(256) void partition_edges(const int* __restrict__ src,
        const int* __restrict__ dst, int* __restrict__ bcursor,
        uint2* __restrict__ pairs, int E) {
    __shared__ int hist[256];
    __shared__ int lbase[256];
    __shared__ int rbase[256];
    __shared__ int sA[256], sB[256];
    __shared__ uint2 st[P2_EPB];
    int tid = threadIdx.x;
    int base = blockIdx.x * P2_EPB;
    hist[tid] = 0;
    __syncthreads();
    int s[8], d[8], lo[8];
    #pragma unroll
    for (int p = 0; p < 8; ++p) {
        int i = base + p * 256 + tid;
        if (i < E) {
            s[p] = src[i]; d[p] = dst[i];
            lo[p] = atomicAdd(&hist[d[p] >> BSHIFT], 1);
        } else d[p] = -1;
    }
    __syncthreads();
    int v = hist[tid];
    sA[tid] = v;
    __syncthreads();
    int* in = sA; int* out = sB;
    #pragma unroll
    for (int off = 1; off < 256; off <<= 1) {
        out[tid] = (tid >= off) ? (in[tid - off] + in[tid]) : in[tid];
        __syncthreads();
        int* t = in; in = out; out = t;
    }
    lbase[tid] = in[tid] - v;
    if (v > 0) rbase[tid] = atomicAdd(&bcursor[tid], v);
    __syncthreads();
    #pragma unroll
    for (int p = 0; p < 8; ++p)
        if (d[p] >= 0)
            st[lbase[d[p] >> BSHIFT] + lo[p]] = make_uint2((unsigned)s[p], (unsigned)d[p]);
    __syncthreads();
    int cnt_total = min(P2_EPB, E - base);
    for (int i = tid; i < cnt_total; i += 256) {
        uint2 pr = st[i];
        int b = (int)(pr.y >> BSHIFT);
        pairs[rbase[b] + (i - lbase[b])] = pr;
    }
}

__global__ __launch_bounds__(256) void build_csr(const uint2* __restrict__ pairs,
        const int* __restrict__ bbase, int* __restrict__ rp, int* __restrict__ csr, int N) {
    __shared__ int hist[256];
    __shared__ int cur[256];
    __shared__ int sA[256], sB[256];
    __shared__ int ordered[P3_CAP];
    int tid = threadIdx.x;
    int b = blockIdx.x;
    int p0 = bbase[b], p1 = bbase[b + 1];
    int cnt = p1 - p0;
    hist[tid] = 0;
    __syncthreads();
    for (int i = tid; i < cnt; i += 256)
        atomicAdd(&hist[pairs[p0 + i].y & 255], 1);
    __syncthreads();
    int v = hist[tid];
    sA[tid] = v;
    __syncthreads();
    int* in = sA; int* out = sB;
    #pragma unroll
    for (int off = 1; off < 256; off <<= 1) {
        out[tid] = (tid >= off) ? (in[tid - off] + in[tid]) : in[tid];
        __syncthreads();
        int* t = in; in = out; out = t;
    }
    int excl = in[tid] - v;
    int dg = (b << BSHIFT) + tid;
    if (dg < N) rp[dg] = p0 + excl;
    cur[tid] = excl;
    __syncthreads();
    if (cnt <= P3_CAP) {
        for (int i = tid; i < cnt; i += 256) {
            uint2 pr = pairs[p0 + i];
            int off = atomicAdd(&cur[pr.y & 255], 1);
            ordered[off] = (int)pr.x;
        }
        __syncthreads();
        for (int i = tid; i < cnt; i += 256)
            csr[p0 + i] = ordered[i];
    } else {
        for (int i = tid; i < cnt; i += 256) {
            uint2 pr = pairs[p0 + i];
            int off = atomicAdd(&cur[pr.y & 255], 1);
            csr[p0 + off] = (int)pr.x;
        }
    }
}

// ================================================================ prep
__global__ void prep_w(const float* __restrict__ W1, const float* __restrict__ W2,
                       short* __restrict__ Wt1b, short* __restrict__ Wt2b) {
    int bid = blockIdx.x, tid = threadIdx.x;
    if (bid < 16) {
        int t = bid * 256 + tid;
        int n = t >> 4, ch = t & 15;
        unsigned short o[8];
        #pragma unroll
        for (int j = 0; j < 8; ++j) {
            int k = ch * 8 + j;
            o[j] = (k < D_IN) ? f2b(W1[(size_t)k * D_HID + n]) : (unsigned short)0;
        }
        *(uint4*)(Wt1b + (size_t)n * 128 + ch * 8) = *(uint4*)o;
    } else {
        int t = (bid - 16) * 256 + tid;
        if (t < 48 * 32) {
            int n = t >> 5, ch = t & 31;
            unsigned short o[8];
            #pragma unroll
            for (int j = 0; j < 8; ++j) {
                int k = ch * 8 + j;
                o[j] = (n < D_OUT) ? f2b(W2[(size_t)k * D_OUT + n]) : (unsigned short)0;
            }
            *(uint4*)(Wt2b + (size_t)n * 256 + ch * 8) = *(uint4*)o;
        }
    }
}

__global__ __launch_bounds__(256) void convert_x(const float* __restrict__ X, short* __restrict__ Xb, int N) {
    int t = blockIdx.x * 256 + threadIdx.x;
    int n = t >> 4, c = t & 15;
    if (n >= N) return;
    unsigned short o[8];
    #pragma unroll
    for (int j = 0; j < 8; ++j) {
        int col = c * 8 + j;
        o[j] = (col < D_IN) ? f2b(X[(size_t)n * D_IN + col]) : (unsigned short)0;
    }
    *(uint4*)(Xb + (size_t)n * 128 + c * 8) = *(uint4*)o;
}

// ================================================================ gather1 (bf16, fp32 accum, 4-deep ILP)
__global__ __launch_bounds__(256) void gather1_bf16(const short* __restrict__ Xb,
        const int* __restrict__ rp, const int* __restrict__ csr,
        short* __restrict__ Ob, int N) {
    int t = blockIdx.x * 256 + threadIdx.x;
    int n = t >> 4, c = t & 15;
    if (n >= N) return;
    const uint4* Xc = (const uint4*)Xb;
    uint4 v = Xc[(size_t)n * 16 + c];
    float acc[8];
    {
        const unsigned short* us = (const unsigned short*)&v;
        #pragma unroll
        for (int j = 0; j < 8; ++j) acc[j] = b2f(us[j]);
    }
    int e0 = rp[n], e1 = rp[n + 1];
    int e = e0;
    for (; e + 4 <= e1; e += 4) {
        int s0 = csr[e], s1 = csr[e + 1], s2 = csr[e + 2], s3 = csr[e + 3];
        uint4 u0 = Xc[(size_t)s0 * 16 + c];
        uint4 u1 = Xc[(size_t)s1 * 16 + c];
        uint4 u2 = Xc[(size_t)s2 * 16 + c];
        uint4 u3 = Xc[(size_t)s3 * 16 + c];
        const unsigned short* p0 = (const unsigned short*)&u0;
        const unsigned short* p1 = (const unsigned short*)&u1;
        const unsigned short* p2 = (const unsigned short*)&u2;
        const unsigned short* p3 = (const unsigned short*)&u3;
        #pragma unroll
        for (int j = 0; j < 8; ++j)
            acc[j] += (b2f(p0[j]) + b2f(p1[j])) + (b2f(p2[j]) + b2f(p3[j]));
    }
    for (; e < e1; ++e) {
        int s = csr[e];
        uint4 u = Xc[(size_t)s * 16 + c];
        const unsigned short* us = (const unsigned short*)&u;
        #pragma unroll
        for (int j = 0; j < 8; ++j) acc[j] += b2f(us[j]);
    }
    unsigned short o[8];
    #pragma unroll
    for (int j = 0; j < 8; ++j) o[j] = f2b(acc[j]);
    *(uint4*)(Ob + (size_t)n * 128 + c * 8) = *(uint4*)o;
}

// ================================================================ GEMM1 (MFMA): hpreb = aggb[N,128] @ W1 + b1 -> bf16 [N][256]
__global__ __launch_bounds__(256) void gemm1_mfma(const short* __restrict__ Ab,
                                                  const short* __restrict__ Wtb,
                                                  const float* __restrict__ bias,
                                                  short* __restrict__ Hb, int N) {
    __shared__ short Al[128 * 136];
    __shared__ short Wl[64 * 136];
    int tid = threadIdx.x;
    int r0 = blockIdx.x * 128;
    int w = tid >> 6, l = tid & 63;
    int r16 = l & 15, g4 = l >> 4;
    int chunk = tid & 15, rbase = tid >> 4;

    #pragma unroll
    for (int p = 0; p < 8; ++p) {
        int row = p * 16 + rbase;
        int m = r0 + row;
        uint4 v = make_uint4(0, 0, 0, 0);
        if (m < N) v = *(const uint4*)(Ab + (size_t)m * 128 + chunk * 8);
        *(uint4*)(Al + row * 136 + chunk * 8) = v;
    }

    bf16x8 af[2][4];
    #pragma unroll
    for (int ct = 0; ct < 4; ++ct) {
        __syncthreads();
        #pragma unroll
        for (int p = 0; p < 4; ++p) {
            int row = p * 16 + rbase;
            *(uint4*)(Wl + row * 136 + chunk * 8) =
                *(const uint4*)(Wtb + (size_t)(ct * 64 + row) * 128 + chunk * 8);
        }
        __syncthreads();
        if (ct == 0) {
            #pragma unroll
            for (int s = 0; s < 2; ++s)
                #pragma unroll
                for (int k = 0; k < 4; ++k)
                    af[s][k] = *(bf16x8*)(Al + (w * 32 + s * 16 + r16) * 136 + k * 32 + g4 * 8);
        }
        bf16x8 wf[4][4];
        #pragma unroll
        for (int n = 0; n < 4; ++n)
            #pragma unroll
            for (int k = 0; k < 4; ++k)
                wf[n][k] = *(bf16x8*)(Wl + (n * 16 + r16) * 136 + k * 32 + g4 * 8);
        #pragma unroll
        for (int s = 0; s < 2; ++s) {
            int m = r0 + w * 32 + s * 16 + r16;
            #pragma unroll
            for (int n = 0; n < 4; ++n) {
                f32x4 acc = {0.f, 0.f, 0.f, 0.f};
                #pragma unroll
                for (int k = 0; k < 4; ++k)
                    acc = __builtin_amdgcn_mfma_f32_16x16x32_bf16(wf[n][k], af[s][k], acc, 0, 0, 0);
                int nc = ct * 64 + n * 16 + g4 * 4;
                float4 b4 = *(const float4*)(bias + nc);
                if (m < N) {
                    ushort4 o;
                    o.x = f2b(acc[0] + b4.x);
                    o.y = f2b(acc[1] + b4.y);
                    o.z = f2b(acc[2] + b4.z);
                    o.w = f2b(acc[3] + b4.w);
                    *(ushort4*)(Hb + (size_t)m * 256 + nc) = o;
                }
            }
        }
    }
}

// ================================================================ column stats bf16 [N][256]
__global__ __launch_bounds__(256) void stats_hid_b(const short* __restrict__ H, int N,
                                                   float* __restrict__ sum, float* __restrict__ sumsq) {
    int c = threadIdx.x;
    const unsigned short* Hu = (const unsigned short*)H;
    float s = 0.f, q = 0.f;
    for (int r = blockIdx.x; r < N; r += gridDim.x) {
        float v = b2f(Hu[(size_t)r * 256 + c]);
        s += v; q += v * v;
    }
    atomicAdd(&sum[c], s);
    atomicAdd(&sumsq[c], q);
}

// ================================================================ GEMM2 (MFMA): z = relu(bn1(hpreb)) @ W2 -> bf16 [N][40]
__global__ __launch_bounds__(256) void gemm2_mfma(const short* __restrict__ Hb,
                                                  const short* __restrict__ Wtb,
                                                  const float* __restrict__ colsum, const float* __restrict__ colsumsq,
                                                  const float* __restrict__ gamma, const float* __restrict__ beta,
                                                  float invN, short* __restrict__ Zb, int N) {
    __shared__ short Al[128 * 136];
    __shared__ short Wl[48 * 136];
    __shared__ float scl[D_HID], shl[D_HID];
    int tid = threadIdx.x;
    {
        float m = colsum[tid] * invN;
        float var = colsumsq[tid] * invN - m * m;
        float rstd = rsqrtf(var + BN_EPS);
        float sc = rstd * gamma[tid];
        scl[tid] = sc;
        shl[tid] = beta[tid] - m * sc;
    }
    int r0 = blockIdx.x * 128;
    int w = tid >> 6, l = tid & 63;
    int r16 = l & 15, g4 = l >> 4;
    int chunk = tid & 15, rbase = tid >> 4;
    f32x4 acc[2][3];
    #pragma unroll
    for (int s = 0; s < 2; ++s)
        #pragma unroll
        for (int n = 0; n < 3; ++n)
            acc[s][n] = (f32x4){0.f, 0.f, 0.f, 0.f};

    #pragma unroll
    for (int h = 0; h < 2; ++h) {
        __syncthreads();
        int kb = h * 128;
        #pragma unroll
        for (int p = 0; p < 8; ++p) {
            int row = p * 16 + rbase;
            int m = r0 + row;
            uint4 v = make_uint4(0, 0, 0, 0);
            if (m < N) v = *(const uint4*)(Hb + (size_t)m * 256 + kb + chunk * 8);
            unsigned short* us = (unsigned short*)&v;
            #pragma unroll
            for (int j = 0; j < 8; ++j) {
                int k = kb + chunk * 8 + j;
                float f = b2f(us[j]);
                f = fmaxf(f * scl[k] + shl[k], 0.f);
                us[j] = f2b(f);
            }
            *(uint4*)(Al + row * 136 + chunk * 8) = v;
        }
        #pragma unroll
        for (int p = 0; p < 3; ++p) {
            int row = p * 16 + rbase;
            *(uint4*)(Wl + row * 136 + chunk * 8) =
                *(const uint4*)(Wtb + (size_t)row * 256 + kb + chunk * 8);
        }
        __syncthreads();
        bf16x8 wf[3][4];
        #pragma unroll
        for (int n = 0; n < 3; ++n)
            #pragma unroll
            for (int k = 0; k < 4; ++k)
                wf[n][k] = *(bf16x8*)(Wl + (n * 16 + r16) * 136 + k * 32 + g4 * 8);
        #pragma unroll
        for (int s = 0; s < 2; ++s) {
            #pragma unroll
            for (int k = 0; k < 4; ++k) {
                bf16x8 af = *(bf16x8*)(Al + (w * 32 + s * 16 + r16) * 136 + k * 32 + g4 * 8);
                #pragma unroll
                for (int n = 0; n < 3; ++n)
                    acc[s][n] = __builtin_amdgcn_mfma_f32_16x16x32_bf16(wf[n][k], af, acc[s][n], 0, 0, 0);
            }
        }
    }
    #pragma unroll
    for (int s = 0; s < 2; ++s) {
        int m = r0 + w * 32 + s * 16 + r16;
        if (m >= N) continue;
        #pragma unroll
        for (int n = 0; n < 3; ++n) {
            int nc = n * 16 + g4 * 4;
            if (nc < D_OUT) {
                ushort4 o;
                o.x = f2b(acc[s][n][0]);
                o.y = f2b(acc[s][n][1]);
                o.z = f2b(acc[s][n][2]);
                o.w = f2b(acc[s][n][3]);
                *(ushort4*)(Zb + (size_t)m * D_OUT + nc) = o;
            }
        }
    }
}

// ================================================================ gather2 + fused column stats (bf16 z, 4-deep ILP)
// thread-per-(n, chunk): 5 chunks of 8 bf16 per row
__global__ __launch_bounds__(256) void gather2_stats(const short* __restrict__ Zb,
        const int* __restrict__ rp, const int* __restrict__ csr,
        const float* __restrict__ bias, float* __restrict__ H2,
        float* __restrict__ gsum, float* __restrict__ gsumsq, int N) {
    __shared__ float ls[D_OUT], lq[D_OUT];
    int tid = threadIdx.x;
    if (tid < D_OUT) { ls[tid] = 0.f; lq[tid] = 0.f; }
    __syncthreads();
    int t = blockIdx.x * 256 + tid;
    int n = t / 5, c = t - n * 5;
    if (n < N) {
        const uint4* Zc = (const uint4*)Zb + c;    // uint4 = 8 bf16; row = 5 uint4
        float acc[8];
        {
            uint4 v = Zc[(size_t)n * 5];
            const unsigned short* us = (const unsigned short*)&v;
            #pragma unroll
            for (int j = 0; j < 8; ++j) acc[j] = b2f(us[j]);
        }
        int e0 = rp[n], e1 = rp[n + 1];
        int e = e0;
        for (; e + 4 <= e1; e += 4) {
            int s0 = csr[e], s1 = csr[e + 1], s2 = csr[e + 2], s3 = csr[e + 3];
            uint4 u0 = Zc[(size_t)s0 * 5];
            uint4 u1 = Zc[(size_t)s1 * 5];
            uint4 u2 = Zc[(size_t)s2 * 5];
            uint4 u3 = Zc[(size_t)s3 * 5];
            const unsigned short* p0 = (const unsigned short*)&u0;
            const unsigned short* p1 = (const unsigned short*)&u1;
            const unsigned short* p2 = (const unsigned short*)&u2;
            const unsigned short* p3 = (const unsigned short*)&u3;
            #pragma unroll
            for (int j = 0; j < 8; ++j)
                acc[j] += (b2f(p0[j]) + b2f(p1[j])) + (b2f(p2[j]) + b2f(p3[j]));
        }
        for (; e < e1; ++e) {
            int s = csr[e];
            uint4 u = Zc[(size_t)s * 5];
            const unsigned short* us = (const unsigned short*)&u;
            #pragma unroll
            for (int j = 0; j < 8; ++j) acc[j] += b2f(us[j]);
        }
        int cc = c * 8;
        float4 o0, o1;
        #pragma unroll
        for (int j = 0; j < 8; ++j) {
            acc[j] += bias[cc + j];
            atomicAdd(&ls[cc + j], acc[j]);
            atomicAdd(&lq[cc + j], acc[j] * acc[j]);
        }
        o0 = make_float4(acc[0], acc[1], acc[2], acc[3]);
        o1 = make_float4(acc[4], acc[5], acc[6], acc[7]);
        *(float4*)(H2 + (size_t)n * D_OUT + cc) = o0;
        *(float4*)(H2 + (size_t)n * D_OUT + cc + 4) = o1;
    }
    __syncthreads();
    if (tid < D_OUT) {
        atomicAdd(&gsum[tid], ls[tid]);
        atomicAdd(&gsumsq[tid], lq[tid]);
    }
}

// ================================================================ BN2 + log_softmax
__global__ __launch_bounds__(256) void bn_logsoftmax(const float* __restrict__ H,
                                                     const float* __restrict__ colsum, const float* __restrict__ colsumsq,
                                                     const float* __restrict__ gamma, const float* __restrict__ beta,
                                                     float invN, float* __restrict__ out, int N) {
    __shared__ float buf[256 * 41];
    __shared__ float scl[D_OUT], shl[D_OUT];
    int tid = threadIdx.x;
    if (tid < D_OUT) {
        float m = colsum[tid] * invN;
        float var = colsumsq[tid] * invN - m * m;
        float rstd = rsqrtf(var + BN_EPS);
        float sc = rstd * gamma[tid];
        scl[tid] = sc;
        shl[tid] = beta[tid] - m * sc;
    }
    int r0 = blockIdx.x * 256;
    int nrow = min(256, N - r0);
    int total = nrow * D_OUT;
    __syncthreads();
    for (int i = tid; i < total; i += 256)
        buf[i + i / D_OUT] = H[(size_t)r0 * D_OUT + i];
    __syncthreads();
    if (tid < nrow) {
        int base = tid * 41;
        float m = -1e30f;
        #pragma unroll
        for (int j = 0; j < D_OUT; ++j) {
            float v = buf[base + j] * scl[j] + shl[j];
            buf[base + j] = v;
            m = fmaxf(m, v);
        }
        float s = 0.f;
        #pragma unroll
        for (int j = 0; j < D_OUT; ++j)
            s += expf(buf[base + j] - m);
        float lse = m + logf(s);
        #pragma unroll
        for (int j = 0; j < D_OUT; ++j)
            buf[base + j] -= lse;
    }
    __syncthreads();
    for (int i = tid; i < total; i += 256)
        out[(size_t)r0 * D_OUT + i] = buf[i + i / D_OUT];
}

// =================================================================
extern "C" void kernel_launch(void* const* d_in, const int* in_sizes, int n_in,
                              void* d_out, int out_size, void* d_ws, size_t ws_size,
                              hipStream_t stream) {
    const float* x      = (const float*)d_in[0];
    const int*   ei     = (const int*)d_in[1];
    const float* W1     = (const float*)d_in[2];
    const float* b1     = (const float*)d_in[3];
    const float* W2     = (const float*)d_in[4];
    const float* b2     = (const float*)d_in[5];
    const float* gamma1 = (const float*)d_in[6];
    const float* beta1  = (const float*)d_in[7];
    const float* gamma2 = (const float*)d_in[8];
    const float* beta2  = (const float*)d_in[9];
    float* out = (float*)d_out;

    const int N = in_sizes[0] / D_IN;      // 50000
    const int E = in_sizes[1] / 2;         // 800000
    const int* src = ei;
    const int* dst = ei + E;
    const int nbk = (N + 255) >> BSHIFT;   // 196

    // ---------------- workspace layout ----------------
    short* xb    = (short*)d_ws;                       // N*128 bf16
    short* aggb  = xb + (size_t)N * 128;               // N*128 bf16
    short* hpreb = aggb + (size_t)N * 128;             // N*256 bf16
    short* Wt1b  = hpreb + (size_t)N * 256;            // 256*128
    short* Wt2b  = Wt1b + 256 * 128;                   // 48*256
    short* zb    = Wt2b + 48 * 256;                    // N*40 bf16
    float* h2    = (float*)(zb + (size_t)N * D_OUT);   // N*40 f32
    float* stats = h2 + (size_t)N * D_OUT;             // 640 f32
    float* colsum1   = stats + 0;     // 256
    float* colsumsq1 = stats + 256;   // 256
    float* colsum2   = stats + 512;   // 40 (pad 64)
    float* colsumsq2 = stats + 576;   // 40 (pad 64)
    int* rp      = (int*)(stats + 640);   // N+1 (pad N+4)
    int* bcnt    = rp + N + 4;            // 256
    int* bbase   = bcnt + 256;            // 260
    int* bcursor = bbase + 260;           // 256
    int* csr     = bcursor + 256;         // E
    uint2* pairs = (uint2*)(csr + E);     // E

    hipMemsetAsync(stats, 0, 640 * sizeof(float), stream);
    hipMemsetAsync(bcnt, 0, 256 * sizeof(int), stream);

    // ---------------- prep + CSR build ----------------
    prep_w<<<22, 256, 0, stream>>>(W1, W2, Wt1b, Wt2b);
    convert_x<<<(N * 16 + 255) / 256, 256, 0, stream>>>(x, xb, N);
    bucket_hist<<<512, 256, 0, stream>>>(dst, bcnt, E);
    bucket_scan<<<1, 256, 0, stream>>>(bcnt, bbase, bcursor, rp, nbk, N, E);
    partition_edges<<<(E + P2_EPB - 1) / P2_EPB, 256, 0, stream>>>(src, dst, bcursor, pairs, E);
    build_csr<<<nbk, 256, 0, stream>>>(pairs, bbase, rp, csr, N);

    // ---------------- layer 1 ----------------
    gather1_bf16<<<(N * 16 + 255) / 256, 256, 0, stream>>>(xb, rp, csr, aggb, N);
    gemm1_mfma<<<(N + 127) / 128, 256, 0, stream>>>(aggb, Wt1b, b1, hpreb, N);
    stats_hid_b<<<512, 256, 0, stream>>>(hpreb, N, colsum1, colsumsq1);

    // ---------------- layer 2 ----------------
    gemm2_mfma<<<(N + 127) / 128, 256, 0, stream>>>(hpreb, Wt2b, colsum1, colsumsq1,
                                                    gamma1, beta1, 1.0f / N, zb, N);
    gather2_stats<<<(N * 5 + 255) / 256, 256, 0, stream>>>(zb, rp, csr, b2, h2,
                                                           colsum2, colsumsq2, N);

    // ---------------- BN2 + log_softmax ----------------
    bn_logsoftmax<<<(N + 255) / 256, 256, 0, stream>>>(h2, colsum2, colsumsq2,
                                                       gamma2, beta2, 1.0f / N, out, N);
}

// Round 9
// 210.923 us; speedup vs baseline: 4.5641x; 1.0299x over previous
//
#include <hip/hip_runtime.h>
#include <hip/hip_bf16.h>

#define D_IN   100
#define D_HID  256
#define D_OUT  40
#define BN_EPS 1e-5f
#define BSHIFT 8
#define P2_EPB 2048
#define P3_CAP 6144

typedef short bf16x8 __attribute__((ext_vector_type(8)));
typedef float f32x4  __attribute__((ext_vector_type(4)));

__device__ inline float b2f(unsigned short u) {
    unsigned int x = ((unsigned int)u) << 16;
    return __builtin_bit_cast(float, x);
}
__device__ inline unsigned short f2b(float f) {
    unsigned int x = __builtin_bit_cast(unsigned int, f);
    unsigned int r = (x + 0x7fffu + ((x >> 16) & 1u)) >> 16;
    return (unsigned short)r;
}

// ================================================================ CSR build (binned, coalesced)
__global__ __launch_bounds__(256) void bucket_hist(const int* __restrict__ dst,
                                                   int* __restrict__ bcnt, int E) {
    __shared__ int h[256];
    int tid = threadIdx.x;
    h[tid] = 0;
    __syncthreads();
    int stride = gridDim.x * blockDim.x;
    for (int i = blockIdx.x * blockDim.x + tid; i < E; i += stride)
        atomicAdd(&h[dst[i] >> BSHIFT], 1);
    __syncthreads();
    if (h[tid]) atomicAdd(&bcnt[tid], h[tid]);
}

__global__ __launch_bounds__(256) void bucket_scan(const int* __restrict__ bcnt,
        int* __restrict__ bbase, int* __restrict__ bcursor, int* __restrict__ rp,
        int NB, int N, int E) {
    __shared__ int A[256], B[256];
    int tid = threadIdx.x;
    int v = (tid < NB) ? bcnt[tid] : 0;
    A[tid] = v;
    __syncthreads();
    int* in = A; int* out = B;
    #pragma unroll
    for (int off = 1; off < 256; off <<= 1) {
        out[tid] = (tid >= off) ? (in[tid - off] + in[tid]) : in[tid];
        __syncthreads();
        int* t = in; in = out; out = t;
    }
    int excl = in[tid] - v;
    if (tid < NB) { bbase[tid] = excl; bcursor[tid] = excl; }
    if (tid == 0) { bbase[NB] = E; rp[N] = E; }
}

__global__ __launch_bounds__(256) void partition_edges(const int* __restrict__ src,
        const int* __restrict__ dst, int* __restrict__ bcursor,
        uint2* __restrict__ pairs, int E) {
    __shared__ int hist[256];
    __shared__ int lbase[256];
    __shared__ int rbase[256];
    __shared__ int sA[256], sB[256];
    __shared__ uint2 st[P2_EPB];
    int tid = threadIdx.x;
    int base = blockIdx.x * P2_EPB;
    hist[tid] = 0;
    __syncthreads();
    int s[8], d[8], lo[8];
    #pragma unroll
    for (int p = 0; p < 8; ++p) {
        int i = base + p * 256 + tid;
        if (i < E) {
            s[p] = src[i]; d[p] = dst[i];
            lo[p] = atomicAdd(&hist[d[p] >> BSHIFT], 1);
        } else d[p] = -1;
    }
    __syncthreads();
    int v = hist[tid];
    sA[tid] = v;
    __syncthreads();
    int* in = sA; int* out = sB;
    #pragma unroll
    for (int off = 1; off < 256; off <<= 1) {
        out[tid] = (tid >= off) ? (in[tid - off] + in[tid]) : in[tid];
        __syncthreads();
        int* t = in; in = out; out = t;
    }
    lbase[tid] = in[tid] - v;
    if (v > 0) rbase[tid] = atomicAdd(&bcursor[tid], v);
    __syncthreads();
    #pragma unroll
    for (int p = 0; p < 8; ++p)
        if (d[p] >= 0)
            st[lbase[d[p] >> BSHIFT] + lo[p]] = make_uint2((unsigned)s[p], (unsigned)d[p]);
    __syncthreads();
    int cnt_total = min(P2_EPB, E - base);
    for (int i = tid; i < cnt_total; i += 256) {
        uint2 pr = st[i];
        int b = (int)(pr.y >> BSHIFT);
        pairs[rbase[b] + (i - lbase[b])] = pr;
    }
}

__global__ __launch_bounds__(256) void build_csr(const uint2* __restrict__ pairs,
        const int* __restrict__ bbase, int* __restrict__ rp, int* __restrict__ csr, int N) {
    __shared__ int hist[256];
    __shared__ int cur[256];
    __shared__ int sA[256], sB[256];
    __shared__ int ordered[P3_CAP];
    int tid = threadIdx.x;
    int b = blockIdx.x;
    int p0 = bbase[b], p1 = bbase[b + 1];
    int cnt = p1 - p0;
    hist[tid] = 0;
    __syncthreads();
    for (int i = tid; i < cnt; i += 256)
        atomicAdd(&hist[pairs[p0 + i].y & 255], 1);
    __syncthreads();
    int v = hist[tid];
    sA[tid] = v;
    __syncthreads();
    int* in = sA; int* out = sB;
    #pragma unroll
    for (int off = 1; off < 256; off <<= 1) {
        out[tid] = (tid >= off) ? (in[tid - off] + in[tid]) : in[tid];
        __syncthreads();
        int* t = in; in = out; out = t;
    }
    int excl = in[tid] - v;
    int dg = (b << BSHIFT) + tid;
    if (dg < N) rp[dg] = p0 + excl;
    cur[tid] = excl;
    __syncthreads();
    if (cnt <= P3_CAP) {
        for (int i = tid; i < cnt; i += 256) {
            uint2 pr = pairs[p0 + i];
            int off = atomicAdd(&cur[pr.y & 255], 1);
            ordered[off] = (int)pr.x;
        }
        __syncthreads();
        for (int i = tid; i < cnt; i += 256)
            csr[p0 + i] = ordered[i];
    } else {
        for (int i = tid; i < cnt; i += 256) {
            uint2 pr = pairs[p0 + i];
            int off = atomicAdd(&cur[pr.y & 255], 1);
            csr[p0 + off] = (int)pr.x;
        }
    }
}

// ================================================================ prep (block 22 zeroes stats + bcnt; replaces slow hipMemsetAsync fills)
__global__ void prep_w(const float* __restrict__ W1, const float* __restrict__ W2,
                       short* __restrict__ Wt1b, short* __restrict__ Wt2b,
                       float* __restrict__ stats, int* __restrict__ bcnt) {
    int bid = blockIdx.x, tid = threadIdx.x;
    if (bid < 16) {
        int t = bid * 256 + tid;
        int n = t >> 4, ch = t & 15;
        unsigned short o[8];
        #pragma unroll
        for (int j = 0; j < 8; ++j) {
            int k = ch * 8 + j;
            o[j] = (k < D_IN) ? f2b(W1[(size_t)k * D_HID + n]) : (unsigned short)0;
        }
        *(uint4*)(Wt1b + (size_t)n * 128 + ch * 8) = *(uint4*)o;
    } else if (bid < 22) {
        int t = (bid - 16) * 256 + tid;
        if (t < 48 * 32) {
            int n = t >> 5, ch = t & 31;
            unsigned short o[8];
            #pragma unroll
            for (int j = 0; j < 8; ++j) {
                int k = ch * 8 + j;
                o[j] = (n < D_OUT) ? f2b(W2[(size_t)k * D_OUT + n]) : (unsigned short)0;
            }
            *(uint4*)(Wt2b + (size_t)n * 256 + ch * 8) = *(uint4*)o;
        }
    } else {
        // zero stats accumulators (640 f32) + bucket counts (256 int)
        bcnt[tid] = 0;
        for (int i = tid; i < 640; i += 256) stats[i] = 0.f;
    }
}

__global__ __launch_bounds__(256) void convert_x(const float* __restrict__ X, short* __restrict__ Xb, int N) {
    int t = blockIdx.x * 256 + threadIdx.x;
    int n = t >> 4, c = t & 15;
    if (n >= N) return;
    unsigned short o[8];
    #pragma unroll
    for (int j = 0; j < 8; ++j) {
        int col = c * 8 + j;
        o[j] = (col < D_IN) ? f2b(X[(size_t)n * D_IN + col]) : (unsigned short)0;
    }
    *(uint4*)(Xb + (size_t)n * 128 + c * 8) = *(uint4*)o;
}

// ================================================================ gather1 (bf16, fp32 accum, 4-deep ILP)
__global__ __launch_bounds__(256) void gather1_bf16(const short* __restrict__ Xb,
        const int* __restrict__ rp, const int* __restrict__ csr,
        short* __restrict__ Ob, int N) {
    int t = blockIdx.x * 256 + threadIdx.x;
    int n = t >> 4, c = t & 15;
    if (n >= N) return;
    const uint4* Xc = (const uint4*)Xb;
    uint4 v = Xc[(size_t)n * 16 + c];
    float acc[8];
    {
        const unsigned short* us = (const unsigned short*)&v;
        #pragma unroll
        for (int j = 0; j < 8; ++j) acc[j] = b2f(us[j]);
    }
    int e0 = rp[n], e1 = rp[n + 1];
    int e = e0;
    for (; e + 4 <= e1; e += 4) {
        int s0 = csr[e], s1 = csr[e + 1], s2 = csr[e + 2], s3 = csr[e + 3];
        uint4 u0 = Xc[(size_t)s0 * 16 + c];
        uint4 u1 = Xc[(size_t)s1 * 16 + c];
        uint4 u2 = Xc[(size_t)s2 * 16 + c];
        uint4 u3 = Xc[(size_t)s3 * 16 + c];
        const unsigned short* p0 = (const unsigned short*)&u0;
        const unsigned short* p1 = (const unsigned short*)&u1;
        const unsigned short* p2 = (const unsigned short*)&u2;
        const unsigned short* p3 = (const unsigned short*)&u3;
        #pragma unroll
        for (int j = 0; j < 8; ++j)
            acc[j] += (b2f(p0[j]) + b2f(p1[j])) + (b2f(p2[j]) + b2f(p3[j]));
    }
    for (; e < e1; ++e) {
        int s = csr[e];
        uint4 u = Xc[(size_t)s * 16 + c];
        const unsigned short* us = (const unsigned short*)&u;
        #pragma unroll
        for (int j = 0; j < 8; ++j) acc[j] += b2f(us[j]);
    }
    unsigned short o[8];
    #pragma unroll
    for (int j = 0; j < 8; ++j) o[j] = f2b(acc[j]);
    *(uint4*)(Ob + (size_t)n * 128 + c * 8) = *(uint4*)o;
}

// ================================================================ GEMM1 (MFMA): hpreb = aggb[N,128] @ W1 + b1 -> bf16 [N][256]
__global__ __launch_bounds__(256) void gemm1_mfma(const short* __restrict__ Ab,
                                                  const short* __restrict__ Wtb,
                                                  const float* __restrict__ bias,
                                                  short* __restrict__ Hb, int N) {
    __shared__ short Al[128 * 136];
    __shared__ short Wl[64 * 136];
    int tid = threadIdx.x;
    int r0 = blockIdx.x * 128;
    int w = tid >> 6, l = tid & 63;
    int r16 = l & 15, g4 = l >> 4;
    int chunk = tid & 15, rbase = tid >> 4;

    #pragma unroll
    for (int p = 0; p < 8; ++p) {
        int row = p * 16 + rbase;
        int m = r0 + row;
        uint4 v = make_uint4(0, 0, 0, 0);
        if (m < N) v = *(const uint4*)(Ab + (size_t)m * 128 + chunk * 8);
        *(uint4*)(Al + row * 136 + chunk * 8) = v;
    }

    bf16x8 af[2][4];
    #pragma unroll
    for (int ct = 0; ct < 4; ++ct) {
        __syncthreads();
        #pragma unroll
        for (int p = 0; p < 4; ++p) {
            int row = p * 16 + rbase;
            *(uint4*)(Wl + row * 136 + chunk * 8) =
                *(const uint4*)(Wtb + (size_t)(ct * 64 + row) * 128 + chunk * 8);
        }
        __syncthreads();
        if (ct == 0) {
            #pragma unroll
            for (int s = 0; s < 2; ++s)
                #pragma unroll
                for (int k = 0; k < 4; ++k)
                    af[s][k] = *(bf16x8*)(Al + (w * 32 + s * 16 + r16) * 136 + k * 32 + g4 * 8);
        }
        bf16x8 wf[4][4];
        #pragma unroll
        for (int n = 0; n < 4; ++n)
            #pragma unroll
            for (int k = 0; k < 4; ++k)
                wf[n][k] = *(bf16x8*)(Wl + (n * 16 + r16) * 136 + k * 32 + g4 * 8);
        #pragma unroll
        for (int s = 0; s < 2; ++s) {
            int m = r0 + w * 32 + s * 16 + r16;
            #pragma unroll
            for (int n = 0; n < 4; ++n) {
                f32x4 acc = {0.f, 0.f, 0.f, 0.f};
                #pragma unroll
                for (int k = 0; k < 4; ++k)
                    acc = __builtin_amdgcn_mfma_f32_16x16x32_bf16(wf[n][k], af[s][k], acc, 0, 0, 0);
                int nc = ct * 64 + n * 16 + g4 * 4;
                float4 b4 = *(const float4*)(bias + nc);
                if (m < N) {
                    ushort4 o;
                    o.x = f2b(acc[0] + b4.x);
                    o.y = f2b(acc[1] + b4.y);
                    o.z = f2b(acc[2] + b4.z);
                    o.w = f2b(acc[3] + b4.w);
                    *(ushort4*)(Hb + (size_t)m * 256 + nc) = o;
                }
            }
        }
    }
}

// ================================================================ column stats bf16 [N][256]
__global__ __launch_bounds__(256) void stats_hid_b(const short* __restrict__ H, int N,
                                                   float* __restrict__ sum, float* __restrict__ sumsq) {
    int c = threadIdx.x;
    const unsigned short* Hu = (const unsigned short*)H;
    float s = 0.f, q = 0.f;
    for (int r = blockIdx.x; r < N; r += gridDim.x) {
        float v = b2f(Hu[(size_t)r * 256 + c]);
        s += v; q += v * v;
    }
    atomicAdd(&sum[c], s);
    atomicAdd(&sumsq[c], q);
}

// ================================================================ GEMM2 (MFMA): z = relu(bn1(hpreb)) @ W2 -> bf16 [N][40]
__global__ __launch_bounds__(256) void gemm2_mfma(const short* __restrict__ Hb,
                                                  const short* __restrict__ Wtb,
                                                  const float* __restrict__ colsum, const float* __restrict__ colsumsq,
                                                  const float* __restrict__ gamma, const float* __restrict__ beta,
                                                  float invN, short* __restrict__ Zb, int N) {
    __shared__ short Al[128 * 136];
    __shared__ short Wl[48 * 136];
    __shared__ float scl[D_HID], shl[D_HID];
    int tid = threadIdx.x;
    {
        float m = colsum[tid] * invN;
        float var = colsumsq[tid] * invN - m * m;
        float rstd = rsqrtf(var + BN_EPS);
        float sc = rstd * gamma[tid];
        scl[tid] = sc;
        shl[tid] = beta[tid] - m * sc;
    }
    int r0 = blockIdx.x * 128;
    int w = tid >> 6, l = tid & 63;
    int r16 = l & 15, g4 = l >> 4;
    int chunk = tid & 15, rbase = tid >> 4;
    f32x4 acc[2][3];
    #pragma unroll
    for (int s = 0; s < 2; ++s)
        #pragma unroll
        for (int n = 0; n < 3; ++n)
            acc[s][n] = (f32x4){0.f, 0.f, 0.f, 0.f};

    #pragma unroll
    for (int h = 0; h < 2; ++h) {
        __syncthreads();
        int kb = h * 128;
        #pragma unroll
        for (int p = 0; p < 8; ++p) {
            int row = p * 16 + rbase;
            int m = r0 + row;
            uint4 v = make_uint4(0, 0, 0, 0);
            if (m < N) v = *(const uint4*)(Hb + (size_t)m * 256 + kb + chunk * 8);
            unsigned short* us = (unsigned short*)&v;
            #pragma unroll
            for (int j = 0; j < 8; ++j) {
                int k = kb + chunk * 8 + j;
                float f = b2f(us[j]);
                f = fmaxf(f * scl[k] + shl[k], 0.f);
                us[j] = f2b(f);
            }
            *(uint4*)(Al + row * 136 + chunk * 8) = v;
        }
        #pragma unroll
        for (int p = 0; p < 3; ++p) {
            int row = p * 16 + rbase;
            *(uint4*)(Wl + row * 136 + chunk * 8) =
                *(const uint4*)(Wtb + (size_t)row * 256 + kb + chunk * 8);
        }
        __syncthreads();
        bf16x8 wf[3][4];
        #pragma unroll
        for (int n = 0; n < 3; ++n)
            #pragma unroll
            for (int k = 0; k < 4; ++k)
                wf[n][k] = *(bf16x8*)(Wl + (n * 16 + r16) * 136 + k * 32 + g4 * 8);
        #pragma unroll
        for (int s = 0; s < 2; ++s) {
            #pragma unroll
            for (int k = 0; k < 4; ++k) {
                bf16x8 af = *(bf16x8*)(Al + (w * 32 + s * 16 + r16) * 136 + k * 32 + g4 * 8);
                #pragma unroll
                for (int n = 0; n < 3; ++n)
                    acc[s][n] = __builtin_amdgcn_mfma_f32_16x16x32_bf16(wf[n][k], af, acc[s][n], 0, 0, 0);
            }
        }
    }
    #pragma unroll
    for (int s = 0; s < 2; ++s) {
        int m = r0 + w * 32 + s * 16 + r16;
        if (m >= N) continue;
        #pragma unroll
        for (int n = 0; n < 3; ++n) {
            int nc = n * 16 + g4 * 4;
            if (nc < D_OUT) {
                ushort4 o;
                o.x = f2b(acc[s][n][0]);
                o.y = f2b(acc[s][n][1]);
                o.z = f2b(acc[s][n][2]);
                o.w = f2b(acc[s][n][3]);
                *(ushort4*)(Zb + (size_t)m * D_OUT + nc) = o;
            }
        }
    }
}

// ================================================================ gather2 + fused column stats (bf16 z, 4-deep ILP)
__global__ __launch_bounds__(256) void gather2_stats(const short* __restrict__ Zb,
        const int* __restrict__ rp, const int* __restrict__ csr,
        const float* __restrict__ bias, float* __restrict__ H2,
        float* __restrict__ gsum, float* __restrict__ gsumsq, int N) {
    __shared__ float ls[D_OUT], lq[D_OUT];
    int tid = threadIdx.x;
    if (tid < D_OUT) { ls[tid] = 0.f; lq[tid] = 0.f; }
    __syncthreads();
    int t = blockIdx.x * 256 + tid;
    int n = t / 5, c = t - n * 5;
    if (n < N) {
        const uint4* Zc = (const uint4*)Zb + c;
        float acc[8];
        {
            uint4 v = Zc[(size_t)n * 5];
            const unsigned short* us = (const unsigned short*)&v;
            #pragma unroll
            for (int j = 0; j < 8; ++j) acc[j] = b2f(us[j]);
        }
        int e0 = rp[n], e1 = rp[n + 1];
        int e = e0;
        for (; e + 4 <= e1; e += 4) {
            int s0 = csr[e], s1 = csr[e + 1], s2 = csr[e + 2], s3 = csr[e + 3];
            uint4 u0 = Zc[(size_t)s0 * 5];
            uint4 u1 = Zc[(size_t)s1 * 5];
            uint4 u2 = Zc[(size_t)s2 * 5];
            uint4 u3 = Zc[(size_t)s3 * 5];
            const unsigned short* p0 = (const unsigned short*)&u0;
            const unsigned short* p1 = (const unsigned short*)&u1;
            const unsigned short* p2 = (const unsigned short*)&u2;
            const unsigned short* p3 = (const unsigned short*)&u3;
            #pragma unroll
            for (int j = 0; j < 8; ++j)
                acc[j] += (b2f(p0[j]) + b2f(p1[j])) + (b2f(p2[j]) + b2f(p3[j]));
        }
        for (; e < e1; ++e) {
            int s = csr[e];
            uint4 u = Zc[(size_t)s * 5];
            const unsigned short* us = (const unsigned short*)&u;
            #pragma unroll
            for (int j = 0; j < 8; ++j) acc[j] += b2f(us[j]);
        }
        int cc = c * 8;
        float4 o0, o1;
        #pragma unroll
        for (int j = 0; j < 8; ++j) {
            acc[j] += bias[cc + j];
            atomicAdd(&ls[cc + j], acc[j]);
            atomicAdd(&lq[cc + j], acc[j] * acc[j]);
        }
        o0 = make_float4(acc[0], acc[1], acc[2], acc[3]);
        o1 = make_float4(acc[4], acc[5], acc[6], acc[7]);
        *(float4*)(H2 + (size_t)n * D_OUT + cc) = o0;
        *(float4*)(H2 + (size_t)n * D_OUT + cc + 4) = o1;
    }
    __syncthreads();
    if (tid < D_OUT) {
        atomicAdd(&gsum[tid], ls[tid]);
        atomicAdd(&gsumsq[tid], lq[tid]);
    }
}

// ================================================================ BN2 + log_softmax
__global__ __launch_bounds__(256) void bn_logsoftmax(const float* __restrict__ H,
                                                     const float* __restrict__ colsum, const float* __restrict__ colsumsq,
                                                     const float* __restrict__ gamma, const float* __restrict__ beta,
                                                     float invN, float* __restrict__ out, int N) {
    __shared__ float buf[256 * 41];
    __shared__ float scl[D_OUT], shl[D_OUT];
    int tid = threadIdx.x;
    if (tid < D_OUT) {
        float m = colsum[tid] * invN;
        float var = colsumsq[tid] * invN - m * m;
        float rstd = rsqrtf(var + BN_EPS);
        float sc = rstd * gamma[tid];
        scl[tid] = sc;
        shl[tid] = beta[tid] - m * sc;
    }
    int r0 = blockIdx.x * 256;
    int nrow = min(256, N - r0);
    int total = nrow * D_OUT;
    __syncthreads();
    for (int i = tid; i < total; i += 256)
        buf[i + i / D_OUT] = H[(size_t)r0 * D_OUT + i];
    __syncthreads();
    if (tid < nrow) {
        int base = tid * 41;
        float m = -1e30f;
        #pragma unroll
        for (int j = 0; j < D_OUT; ++j) {
            float v = buf[base + j] * scl[j] + shl[j];
            buf[base + j] = v;
            m = fmaxf(m, v);
        }
        float s = 0.f;
        #pragma unroll
        for (int j = 0; j < D_OUT; ++j)
            s += expf(buf[base + j] - m);
        float lse = m + logf(s);
        #pragma unroll
        for (int j = 0; j < D_OUT; ++j)
            buf[base + j] -= lse;
    }
    __syncthreads();
    for (int i = tid; i < total; i += 256)
        out[(size_t)r0 * D_OUT + i] = buf[i + i / D_OUT];
}

// =================================================================
extern "C" void kernel_launch(void* const* d_in, const int* in_sizes, int n_in,
                              void* d_out, int out_size, void* d_ws, size_t ws_size,
                              hipStream_t stream) {
    const float* x      = (const float*)d_in[0];
    const int*   ei     = (const int*)d_in[1];
    const float* W1     = (const float*)d_in[2];
    const float* b1     = (const float*)d_in[3];
    const float* W2     = (const float*)d_in[4];
    const float* b2     = (const float*)d_in[5];
    const float* gamma1 = (const float*)d_in[6];
    const float* beta1  = (const float*)d_in[7];
    const float* gamma2 = (const float*)d_in[8];
    const float* beta2  = (const float*)d_in[9];
    float* out = (float*)d_out;

    const int N = in_sizes[0] / D_IN;      // 50000
    const int E = in_sizes[1] / 2;         // 800000
    const int* src = ei;
    const int* dst = ei + E;
    const int nbk = (N + 255) >> BSHIFT;   // 196

    // ---------------- workspace layout ----------------
    short* xb    = (short*)d_ws;                       // N*128 bf16
    short* aggb  = xb + (size_t)N * 128;               // N*128 bf16
    short* hpreb = aggb + (size_t)N * 128;             // N*256 bf16
    short* Wt1b  = hpreb + (size_t)N * 256;            // 256*128
    short* Wt2b  = Wt1b + 256 * 128;                   // 48*256
    short* zb    = Wt2b + 48 * 256;                    // N*40 bf16
    float* h2    = (float*)(zb + (size_t)N * D_OUT);   // N*40 f32
    float* stats = h2 + (size_t)N * D_OUT;             // 640 f32
    float* colsum1   = stats + 0;     // 256
    float* colsumsq1 = stats + 256;   // 256
    float* colsum2   = stats + 512;   // 40 (pad 64)
    float* colsumsq2 = stats + 576;   // 40 (pad 64)
    int* rp      = (int*)(stats + 640);   // N+1 (pad N+4)
    int* bcnt    = rp + N + 4;            // 256
    int* bbase   = bcnt + 256;            // 260
    int* bcursor = bbase + 260;           // 256
    int* csr     = bcursor + 256;         // E
    uint2* pairs = (uint2*)(csr + E);     // E

    // ---------------- prep (incl. zero-init of stats+bcnt) + CSR build ----------------
    prep_w<<<23, 256, 0, stream>>>(W1, W2, Wt1b, Wt2b, stats, bcnt);
    convert_x<<<(N * 16 + 255) / 256, 256, 0, stream>>>(x, xb, N);
    bucket_hist<<<512, 256, 0, stream>>>(dst, bcnt, E);
    bucket_scan<<<1, 256, 0, stream>>>(bcnt, bbase, bcursor, rp, nbk, N, E);
    partition_edges<<<(E + P2_EPB - 1) / P2_EPB, 256, 0, stream>>>(src, dst, bcursor, pairs, E);
    build_csr<<<nbk, 256, 0, stream>>>(pairs, bbase, rp, csr, N);

    // ---------------- layer 1 ----------------
    gather1_bf16<<<(N * 16 + 255) / 256, 256, 0, stream>>>(xb, rp, csr, aggb, N);
    gemm1_mfma<<<(N + 127) / 128, 256, 0, stream>>>(aggb, Wt1b, b1, hpreb, N);
    stats_hid_b<<<512, 256, 0, stream>>>(hpreb, N, colsum1, colsumsq1);

    // ---------------- layer 2 ----------------
    gemm2_mfma<<<(N + 127) / 128, 256, 0, stream>>>(hpreb, Wt2b, colsum1, colsumsq1,
                                                    gamma1, beta1, 1.0f / N, zb, N);
    gather2_stats<<<(N * 5 + 255) / 256, 256, 0, stream>>>(zb, rp, csr, b2, h2,
                                                           colsum2, colsumsq2, N);

    // ---------------- BN2 + log_softmax ----------------
    bn_logsoftmax<<<(N + 255) / 256, 256, 0, stream>>>(h2, colsum2, colsumsq2,
                                                       gamma2, beta2, 1.0f / N, out, N);
}